// Round 1
// baseline (645.099 us; speedup 1.0000x reference)
//
#include <hip/hip_runtime.h>
#include <hip/hip_bf16.h>
#include <stdint.h>

#define B_ 4
#define L_ 2048
#define H_ 8
#define DK 64
#define M_ 256
#define DIM_ 512
#define NTOK (B_ * L_)      // 8192
#define CHK 128
#define NC (L_ / CHK)       // 16
#define RATIO 0.0625f       // 1/sqrt(256)
#define STABC 1e-5f

__device__ __forceinline__ uint32_t f2bf_rne(float f) {
  uint32_t u = __float_as_uint(f);
  return (u + 0x7fffu + ((u >> 16) & 1u)) >> 16;   // bf16 RNE, low 16 bits
}
__device__ __forceinline__ float bf2f(uint32_t lo16) { return __uint_as_float(lo16 << 16); }
__device__ __forceinline__ float bf_lo(uint32_t u) { return __uint_as_float(u << 16); }
__device__ __forceinline__ float bf_hi(uint32_t u) { return __uint_as_float(u & 0xffff0000u); }

// ---------- Y[R,512] = X[R,512] @ W[512,512]^T + bias ----------
__global__ __launch_bounds__(256) void gemm_bias(const float* __restrict__ X,
                                                 const float* __restrict__ W,
                                                 const float* __restrict__ bias,
                                                 float* __restrict__ Y) {
  __shared__ float As[16][68];   // [k][m], pad 68 keeps float4 alignment (272B rows)
  __shared__ float Bs[16][68];
  const int bm = blockIdx.x * 64, bn = blockIdx.y * 64;
  const int tid = threadIdx.x;
  const int tr = tid >> 4, tc = tid & 15;
  float acc[4][4] = {};
  for (int k0 = 0; k0 < DIM_; k0 += 16) {
#pragma unroll
    for (int i = 0; i < 4; ++i) {
      int e = tid + i * 256;
      int m = e >> 4, k = e & 15;
      As[k][m] = X[(size_t)(bm + m) * DIM_ + k0 + k];
      Bs[k][m] = W[(size_t)(bn + m) * DIM_ + k0 + k];
    }
    __syncthreads();
#pragma unroll
    for (int k = 0; k < 16; ++k) {
      float4 a0 = *(const float4*)&As[k][tr * 4];
      float4 b0 = *(const float4*)&Bs[k][tc * 4];
      float a[4] = {a0.x, a0.y, a0.z, a0.w};
      float b[4] = {b0.x, b0.y, b0.z, b0.w};
#pragma unroll
      for (int i = 0; i < 4; ++i)
#pragma unroll
        for (int j = 0; j < 4; ++j) acc[i][j] += a[i] * b[j];
    }
    __syncthreads();
  }
  float4 bias4 = *(const float4*)&bias[bn + tc * 4];
#pragma unroll
  for (int i = 0; i < 4; ++i) {
    int m = bm + tr * 4 + i;
    float4 o;
    o.x = acc[i][0] + bias4.x;
    o.y = acc[i][1] + bias4.y;
    o.z = acc[i][2] + bias4.z;
    o.w = acc[i][3] + bias4.w;
    *(float4*)&Y[(size_t)m * DIM_ + bn + tc * 4] = o;
  }
}

// ---------- phi = relu(RATIO * Z_head @ proj^T) + STAB -> bf16 [BH, L, M] ----------
__global__ __launch_bounds__(256) void feat_kernel(const float* __restrict__ Z,
                                                   const float* __restrict__ proj,
                                                   unsigned short* __restrict__ outp) {
  const int lt = blockIdx.x, bh = blockIdx.y;
  const int b = bh >> 3, h = bh & 7;
  const int l0 = lt * 64;
  __shared__ float Zs[64][DK];
  const int tid = threadIdx.x;
#pragma unroll
  for (int i = 0; i < 16; ++i) {
    int e = tid + i * 256;
    int l = e >> 6, d = e & 63;
    Zs[l][d] = Z[(size_t)(b * L_ + l0 + l) * DIM_ + h * DK + d];
  }
  float4 pr[16];
#pragma unroll
  for (int i = 0; i < 16; ++i) pr[i] = *(const float4*)&proj[tid * DK + i * 4];
  __syncthreads();
  size_t base = ((size_t)bh * L_ + l0) * M_;
  for (int l = 0; l < 64; ++l) {
    const float4* zr = (const float4*)&Zs[l][0];
    float acc = 0.f;
#pragma unroll
    for (int i = 0; i < 16; ++i) {
      float4 z = zr[i];
      acc += z.x * pr[i].x + z.y * pr[i].y + z.z * pr[i].z + z.w * pr[i].w;
    }
    float v = fmaxf(RATIO * acc, 0.f) + STABC;
    outp[base + (size_t)l * M_ + tid] = (unsigned short)f2bf_rne(v);
  }
}

// ---------- per-chunk partial states: S_kv[m,d] = sum_l kp*v ; s_k[m] = sum_l kp ----------
__global__ __launch_bounds__(256) void chunk_partial(const unsigned short* __restrict__ kp,
                                                     const float* __restrict__ V,
                                                     float* __restrict__ Skv,
                                                     float* __restrict__ sk) {
  const int ci = blockIdx.x, bh = blockIdx.y;
  const int b = bh >> 3, h = bh & 7;
  const int l0 = ci * CHK;
  __shared__ float vs[CHK][DK];
  const int tid = threadIdx.x;
#pragma unroll
  for (int i = 0; i < 32; ++i) {
    int e = tid + i * 256;
    int l = e >> 6, d = e & 63;
    vs[l][d] = V[(size_t)(b * L_ + l0 + l) * DIM_ + h * DK + d];
  }
  __syncthreads();
  const int m = tid;
  float4 acc4[16] = {};
  float ks = 0.f;
  const unsigned short* kpb = kp + ((size_t)bh * L_ + l0) * M_;
  for (int l = 0; l < CHK; ++l) {
    float kv = bf2f(kpb[(size_t)l * M_ + m]);
    ks += kv;
    const float4* vr = (const float4*)&vs[l][0];
#pragma unroll
    for (int i = 0; i < 16; ++i) {
      float4 v = vr[i];
      acc4[i].x += kv * v.x;
      acc4[i].y += kv * v.y;
      acc4[i].z += kv * v.z;
      acc4[i].w += kv * v.w;
    }
  }
  float* so = Skv + (((size_t)bh * NC + ci) * M_ + m) * DK;
#pragma unroll
  for (int i = 0; i < 16; ++i) *(float4*)&so[i * 4] = acc4[i];
  sk[((size_t)bh * NC + ci) * M_ + m] = ks;
}

// ---------- in-place exclusive prefix over chunks ----------
__global__ __launch_bounds__(256) void prefix_kernel(float* __restrict__ Skv,
                                                     float* __restrict__ sk) {
  const int sl = blockIdx.x, bh = blockIdx.y;   // slice 0..7
  const int tid = threadIdx.x;
  const int base_e = sl * 2048 + tid;
  float carry[8] = {};
  float ck = 0.f;
  for (int ci = 0; ci < NC; ++ci) {
    float* p = Skv + ((size_t)bh * NC + ci) * (M_ * DK);
#pragma unroll
    for (int i = 0; i < 8; ++i) {
      int e = base_e + i * 256;
      float t = p[e];
      p[e] = carry[i];
      carry[i] += t;
    }
    if (sl == 0) {
      float* pk = sk + ((size_t)bh * NC + ci) * M_;
      float t = pk[tid];
      pk[tid] = ck;
      ck += t;
    }
  }
}

// ---------- A[l, j] = causal-masked qp[l] . kp[j]  (within chunk), bf16 ----------
__global__ __launch_bounds__(256) void qk_chunk(const unsigned short* __restrict__ qp,
                                                const unsigned short* __restrict__ kp,
                                                unsigned short* __restrict__ A) {
  const int ci = blockIdx.x, bh = blockIdx.y;
  const int l0 = ci * CHK;
  __shared__ float qs[32][132];   // [k][row], 132 keeps float4-aligned rows (528B)
  __shared__ float ks_[32][132];
  const int tid = threadIdx.x;
  const int tr = tid >> 4, tc = tid & 15;
  float acc[8][8] = {};
  const unsigned short* qpb = qp + ((size_t)bh * L_ + l0) * M_;
  const unsigned short* kpb = kp + ((size_t)bh * L_ + l0) * M_;
  for (int k0 = 0; k0 < M_; k0 += 32) {
#pragma unroll
    for (int i = 0; i < 16; ++i) {
      int e = tid + i * 256;
      int r = e >> 5, k = e & 31;
      qs[k][r] = bf2f(qpb[(size_t)r * M_ + k0 + k]);
      ks_[k][r] = bf2f(kpb[(size_t)r * M_ + k0 + k]);
    }
    __syncthreads();
#pragma unroll
    for (int k = 0; k < 32; ++k) {
      float4 a0 = *(const float4*)&qs[k][tr * 8];
      float4 a1 = *(const float4*)&qs[k][tr * 8 + 4];
      float4 b0 = *(const float4*)&ks_[k][tc * 8];
      float4 b1 = *(const float4*)&ks_[k][tc * 8 + 4];
      float a[8] = {a0.x, a0.y, a0.z, a0.w, a1.x, a1.y, a1.z, a1.w};
      float b[8] = {b0.x, b0.y, b0.z, b0.w, b1.x, b1.y, b1.z, b1.w};
#pragma unroll
      for (int i = 0; i < 8; ++i)
#pragma unroll
        for (int j = 0; j < 8; ++j) acc[i][j] += a[i] * b[j];
    }
    __syncthreads();
  }
  unsigned short* Ab = A + ((size_t)bh * L_ + l0) * CHK;
#pragma unroll
  for (int i = 0; i < 8; ++i) {
    int li = tr * 8 + i;
#pragma unroll
    for (int j = 0; j < 8; ++j) {
      int jj = tc * 8 + j;
      float v = (jj <= li) ? acc[i][j] : 0.f;    // inclusive causal mask
      Ab[(size_t)li * CHK + jj] = (unsigned short)f2bf_rne(v);
    }
  }
}

// ---------- attn = (A@v + qp@S_prev) / (rowsum(A) + qp.sk_prev) ----------
__global__ __launch_bounds__(256) void out_chunk(const unsigned short* __restrict__ qp,
                                                 const unsigned short* __restrict__ A,
                                                 const float* __restrict__ V,
                                                 const float* __restrict__ Skv,
                                                 const float* __restrict__ sk,
                                                 float* __restrict__ attn) {
  const int ci = blockIdx.x, bh = blockIdx.y;
  const int b = bh >> 3, h = bh & 7;
  const int l0 = ci * CHK;
  __shared__ uint32_t As_s[CHK * 65];   // bf16-pair rows, stride 65 avoids 32-way bank conflict
  __shared__ uint32_t vs_s[CHK * 32];   // v rows as bf16 pairs
  __shared__ uint32_t Ss_s[64 * 32];    // S_kv tile as bf16 pairs
  const int tid = threadIdx.x;
  const uint32_t* Ag = (const uint32_t*)(A + ((size_t)bh * L_ + l0) * CHK);
#pragma unroll
  for (int i = 0; i < 32; ++i) {
    int e = tid + i * 256;
    int r = e >> 6, c = e & 63;
    As_s[r * 65 + c] = Ag[e];
  }
#pragma unroll
  for (int i = 0; i < 8; ++i) {
    int e = tid + i * 256;            // float4 index over [128][16]
    int l = e >> 4, d4 = e & 15;
    float4 f = *(const float4*)&V[(size_t)(b * L_ + l0 + l) * DIM_ + h * DK + d4 * 4];
    vs_s[l * 32 + d4 * 2]     = f2bf_rne(f.x) | (f2bf_rne(f.y) << 16);
    vs_s[l * 32 + d4 * 2 + 1] = f2bf_rne(f.z) | (f2bf_rne(f.w) << 16);
  }
  __syncthreads();
  const int l = tid >> 1, half = tid & 1;   // 2 threads per row, 32 d each
  float acc[32] = {};
  float den = 0.f;
  // intra-chunk: num += A[l,j] * v[j,:], den += A[l,j]
  for (int j2 = 0; j2 < CHK / 2; ++j2) {
    uint32_t au = As_s[l * 65 + j2];
    float ax = bf_lo(au), ay = bf_hi(au);
    den += ax + ay;
    const uint4* v0 = (const uint4*)&vs_s[(2 * j2) * 32 + half * 16];
    const uint4* v1 = (const uint4*)&vs_s[(2 * j2 + 1) * 32 + half * 16];
#pragma unroll
    for (int q = 0; q < 4; ++q) {
      uint4 u = v0[q], w = v1[q];
      acc[q * 8 + 0] += ax * bf_lo(u.x) + ay * bf_lo(w.x);
      acc[q * 8 + 1] += ax * bf_hi(u.x) + ay * bf_hi(w.x);
      acc[q * 8 + 2] += ax * bf_lo(u.y) + ay * bf_lo(w.y);
      acc[q * 8 + 3] += ax * bf_hi(u.y) + ay * bf_hi(w.y);
      acc[q * 8 + 4] += ax * bf_lo(u.z) + ay * bf_lo(w.z);
      acc[q * 8 + 5] += ax * bf_hi(u.z) + ay * bf_hi(w.z);
      acc[q * 8 + 6] += ax * bf_lo(u.w) + ay * bf_lo(w.w);
      acc[q * 8 + 7] += ax * bf_hi(u.w) + ay * bf_hi(w.w);
    }
  }
  // inter-chunk: num += qp[l,m] * S_prev[m,:], den += qp[l,m] * sk_prev[m]
  const uint32_t* qp2 = (const uint32_t*)(qp + ((size_t)bh * L_ + l0 + l) * M_);
  const float* Sb = Skv + ((size_t)bh * NC + ci) * (size_t)(M_ * DK);
  const float* skb = sk + ((size_t)bh * NC + ci) * M_;
  for (int m0 = 0; m0 < M_; m0 += 64) {
    __syncthreads();
#pragma unroll
    for (int i = 0; i < 4; ++i) {
      int e = tid + i * 256;          // float4 index over [64][16]
      int mm = e >> 4, d4 = e & 15;
      float4 f = *(const float4*)&Sb[(size_t)(m0 + mm) * DK + d4 * 4];
      Ss_s[mm * 32 + d4 * 2]     = f2bf_rne(f.x) | (f2bf_rne(f.y) << 16);
      Ss_s[mm * 32 + d4 * 2 + 1] = f2bf_rne(f.z) | (f2bf_rne(f.w) << 16);
    }
    __syncthreads();
    for (int m2 = 0; m2 < 32; ++m2) {
      uint32_t qu = qp2[(m0 >> 1) + m2];
      float qx = bf_lo(qu), qy = bf_hi(qu);
      den += qx * skb[m0 + 2 * m2] + qy * skb[m0 + 2 * m2 + 1];
      const uint4* s0 = (const uint4*)&Ss_s[(2 * m2) * 32 + half * 16];
      const uint4* s1 = (const uint4*)&Ss_s[(2 * m2 + 1) * 32 + half * 16];
#pragma unroll
      for (int q = 0; q < 4; ++q) {
        uint4 u = s0[q], w = s1[q];
        acc[q * 8 + 0] += qx * bf_lo(u.x) + qy * bf_lo(w.x);
        acc[q * 8 + 1] += qx * bf_hi(u.x) + qy * bf_hi(w.x);
        acc[q * 8 + 2] += qx * bf_lo(u.y) + qy * bf_lo(w.y);
        acc[q * 8 + 3] += qx * bf_hi(u.y) + qy * bf_hi(w.y);
        acc[q * 8 + 4] += qx * bf_lo(u.z) + qy * bf_lo(w.z);
        acc[q * 8 + 5] += qx * bf_hi(u.z) + qy * bf_hi(w.z);
        acc[q * 8 + 6] += qx * bf_lo(u.w) + qy * bf_lo(w.w);
        acc[q * 8 + 7] += qx * bf_hi(u.w) + qy * bf_hi(w.w);
      }
    }
  }
  float inv = 1.f / den;
  float* ob = attn + ((size_t)(b * L_ + l0 + l)) * DIM_ + h * DK + half * 32;
#pragma unroll
  for (int q = 0; q < 8; ++q) {
    float4 o;
    o.x = acc[q * 4 + 0] * inv;
    o.y = acc[q * 4 + 1] * inv;
    o.z = acc[q * 4 + 2] * inv;
    o.w = acc[q * 4 + 3] * inv;
    *(float4*)&ob[q * 4] = o;
  }
}

extern "C" void kernel_launch(void* const* d_in, const int* in_sizes, int n_in,
                              void* d_out, int out_size, void* d_ws, size_t ws_size,
                              hipStream_t stream) {
  const float* query = (const float*)d_in[0];
  const float* key   = (const float*)d_in[1];
  const float* value = (const float*)d_in[2];
  const float* proj  = (const float*)d_in[3];
  const float* wq = (const float*)d_in[4];
  const float* bq = (const float*)d_in[5];
  const float* wk = (const float*)d_in[6];
  const float* bk = (const float*)d_in[7];
  const float* wv = (const float*)d_in[8];
  const float* bv = (const float*)d_in[9];
  const float* wo = (const float*)d_in[10];
  const float* bo = (const float*)d_in[11];

  char* ws = (char*)d_ws;
  const size_t SZ_QKV = (size_t)NTOK * DIM_ * 4;        // 16 MB each
  const size_t SZ_PHI = (size_t)B_ * H_ * L_ * M_ * 2;  // 32 MB each (bf16)
  const size_t SZ_SKV = (size_t)B_ * H_ * NC * M_ * DK * 4;
  float* Q = (float*)(ws);
  float* K = (float*)(ws + SZ_QKV);
  float* V = (float*)(ws + 2 * SZ_QKV);
  unsigned short* qp = (unsigned short*)(ws + 3 * SZ_QKV);
  unsigned short* kp = (unsigned short*)(ws + 3 * SZ_QKV + SZ_PHI);
  float* Skv = (float*)(ws + 3 * SZ_QKV + 2 * SZ_PHI);
  float* sk  = (float*)(ws + 3 * SZ_QKV + 2 * SZ_PHI + SZ_SKV);
  unsigned short* Abuf = (unsigned short*)K;   // K dead after feat -> reuse for A (16 MB bf16)
  float* attn = Q;                              // Q dead after feat -> reuse for attn

  dim3 blk(256);
  dim3 gg(NTOK / 64, DIM_ / 64);
  gemm_bias<<<gg, blk, 0, stream>>>(query, wq, bq, Q);
  gemm_bias<<<gg, blk, 0, stream>>>(key,   wk, bk, K);
  gemm_bias<<<gg, blk, 0, stream>>>(value, wv, bv, V);
  feat_kernel<<<dim3(L_ / 64, B_ * H_), blk, 0, stream>>>(Q, proj, qp);
  feat_kernel<<<dim3(L_ / 64, B_ * H_), blk, 0, stream>>>(K, proj, kp);
  chunk_partial<<<dim3(NC, B_ * H_), blk, 0, stream>>>(kp, V, Skv, sk);
  prefix_kernel<<<dim3(8, B_ * H_), blk, 0, stream>>>(Skv, sk);
  qk_chunk<<<dim3(NC, B_ * H_), blk, 0, stream>>>(qp, kp, Abuf);
  out_chunk<<<dim3(NC, B_ * H_), blk, 0, stream>>>(qp, Abuf, V, Skv, sk, attn);
  gemm_bias<<<gg, blk, 0, stream>>>(attn, wo, bo, (float*)d_out);
}

// Round 2
// 166.094 us; speedup vs baseline: 3.8839x; 3.8839x over previous
//
#include <hip/hip_runtime.h>
#include <stdint.h>

#define B_ 4
#define L_ 2048
#define H_ 8
#define DK 64
#define M_ 256
#define DIM_ 512
#define NTOK (B_ * L_)
#define CHK 128
#define NC (L_ / CHK)
#define BH (B_ * H_)
#define RATIO 0.0625f
#define STABC 1e-5f

typedef unsigned short ushort_t;
typedef __attribute__((ext_vector_type(8))) short bf8v;   // 8 bf16 = 4 VGPR
typedef __attribute__((ext_vector_type(4))) float f4v;    // MFMA accumulator

#define MFMA16(a, b, c) __builtin_amdgcn_mfma_f32_16x16x32_bf16(a, b, c, 0, 0, 0)

__device__ __forceinline__ ushort_t f2bf(float f) {
  uint32_t u = __float_as_uint(f);
  return (ushort_t)((u + 0x7fffu + ((u >> 16) & 1u)) >> 16);
}
__device__ __forceinline__ float bf2f(ushort_t u) { return __uint_as_float(((uint32_t)u) << 16); }

// async global->LDS, 16B per lane; LDS dest = wave-uniform base + lane*16
__device__ __forceinline__ void gll16(const void* g, void* l) {
  __builtin_amdgcn_global_load_lds((const __attribute__((address_space(1))) void*)g,
                                   (__attribute__((address_space(3))) void*)l, 16, 0, 0);
}

// LDS tile row stride = 64 bf16 = 128 B everywhere; XOR-swizzled (T2-style):
// physical byte = row*128 + (logical_col_byte ^ ((row&7)<<4))
__device__ __forceinline__ bf8v ldfrag(const ushort_t* base, int row, int cb) {
  return *(const bf8v*)((const char*)base + row * 128 + (cb ^ ((row & 7) << 4)));
}

// ---------------- converts ----------------
__global__ __launch_bounds__(256) void cvt_k(const float* __restrict__ s, ushort_t* __restrict__ d) {
  int i = (blockIdx.x * 256 + threadIdx.x) * 8;
  float4 a = *(const float4*)(s + i);
  float4 b = *(const float4*)(s + i + 4);
  union { ushort_t u[8]; uint4 v; } o;
  o.u[0] = f2bf(a.x); o.u[1] = f2bf(a.y); o.u[2] = f2bf(a.z); o.u[3] = f2bf(a.w);
  o.u[4] = f2bf(b.x); o.u[5] = f2bf(b.y); o.u[6] = f2bf(b.z); o.u[7] = f2bf(b.w);
  *(uint4*)(d + i) = o.v;
}

__global__ __launch_bounds__(256) void cvt_w_k(const float* __restrict__ w0, const float* __restrict__ w1,
                                               const float* __restrict__ w2, const float* __restrict__ w3,
                                               const float* __restrict__ pj, ushort_t* __restrict__ d) {
  int i = (blockIdx.x * 256 + threadIdx.x) * 8;   // grid covers exactly 4*2^18 + 2^14 elems
  int seg = i >> 18;
  const float* s;
  int off;
  if (seg == 0) { s = w0; off = i; }
  else if (seg == 1) { s = w1; off = i - 262144; }
  else if (seg == 2) { s = w2; off = i - 524288; }
  else if (seg == 3) { s = w3; off = i - 786432; }
  else { s = pj; off = i - 1048576; }
  float4 a = *(const float4*)(s + off);
  float4 b = *(const float4*)(s + off + 4);
  union { ushort_t u[8]; uint4 v; } o;
  o.u[0] = f2bf(a.x); o.u[1] = f2bf(a.y); o.u[2] = f2bf(a.z); o.u[3] = f2bf(a.w);
  o.u[4] = f2bf(b.x); o.u[5] = f2bf(b.y); o.u[6] = f2bf(b.z); o.u[7] = f2bf(b.w);
  *(uint4*)(d + i) = o.v;
}

// ---------------- Y[8192,512] = X @ W^T + bias  (bf16 MFMA, 128x128 tile) ----------------
template <int OUTBF>
__global__ __launch_bounds__(256) void gemm512_k(const ushort_t* __restrict__ A, const ushort_t* __restrict__ Bw,
                                                 const float* __restrict__ bias, void* __restrict__ Y) {
  __shared__ ushort_t As[128 * 64];
  __shared__ ushort_t Bs[128 * 64];
  const int tid = threadIdx.x, lane = tid & 63, w = tid >> 6;
  const int bm = blockIdx.x * 128, bn = blockIdx.y * 128;
  const int srow = w * 8 + (lane >> 3);
  const int scol = (((lane & 7) * 16) ^ ((lane >> 3) << 4)) >> 1;   // swizzled source col (elems)
  const int wr = (w >> 1) * 64, wc = (w & 1) * 64;
  const int fr = lane & 15, ks = lane >> 4;
  f4v acc[4][4] = {};
  for (int k0 = 0; k0 < DIM_; k0 += 64) {
#pragma unroll
    for (int i = 0; i < 4; ++i) {
      int r = i * 32 + srow;
      gll16(A + (size_t)(bm + r) * DIM_ + k0 + scol, (char*)As + i * 4096 + w * 1024);
      gll16(Bw + (size_t)(bn + r) * DIM_ + k0 + scol, (char*)Bs + i * 4096 + w * 1024);
    }
    __syncthreads();
#pragma unroll
    for (int kk = 0; kk < 2; ++kk) {
      const int cb = kk * 64 + ks * 16;
      bf8v av[4], bv[4];
#pragma unroll
      for (int m = 0; m < 4; ++m) av[m] = ldfrag(As, wr + m * 16 + fr, cb);
#pragma unroll
      for (int n = 0; n < 4; ++n) bv[n] = ldfrag(Bs, wc + n * 16 + fr, cb);
#pragma unroll
      for (int m = 0; m < 4; ++m)
#pragma unroll
        for (int n = 0; n < 4; ++n) acc[m][n] = MFMA16(av[m], bv[n], acc[m][n]);
    }
    __syncthreads();
  }
  const int fq = lane >> 4;
#pragma unroll
  for (int m = 0; m < 4; ++m)
#pragma unroll
    for (int n = 0; n < 4; ++n) {
      int col = bn + wc + n * 16 + fr;
      float bsv = bias[col];
#pragma unroll
      for (int j = 0; j < 4; ++j) {
        int row = bm + wr + m * 16 + fq * 4 + j;
        float v = acc[m][n][j] + bsv;
        if (OUTBF) ((ushort_t*)Y)[(size_t)row * DIM_ + col] = f2bf(v);
        else ((float*)Y)[(size_t)row * DIM_ + col] = v;
      }
    }
}

// ---------------- phi = relu(RATIO * X_head @ proj^T) + STAB -> bf16 [bh][L][M] ----------------
__global__ __launch_bounds__(256) void feat_k(const ushort_t* __restrict__ X, const ushort_t* __restrict__ P,
                                              ushort_t* __restrict__ out) {
  __shared__ ushort_t As[128 * 64];
  __shared__ ushort_t Bs[128 * 64];
  const int tid = threadIdx.x, lane = tid & 63, w = tid >> 6;
  const int bm = blockIdx.x * 128, bn = blockIdx.y * 128, h = blockIdx.z;
  const int srow = w * 8 + (lane >> 3);
  const int scol = (((lane & 7) * 16) ^ ((lane >> 3) << 4)) >> 1;
  const int wr = (w >> 1) * 64, wc = (w & 1) * 64;
  const int fr = lane & 15, ks = lane >> 4;
  f4v acc[4][4] = {};
#pragma unroll
  for (int i = 0; i < 4; ++i) {
    int r = i * 32 + srow;
    gll16(X + (size_t)(bm + r) * DIM_ + h * 64 + scol, (char*)As + i * 4096 + w * 1024);
    gll16(P + (size_t)(bn + r) * 64 + scol, (char*)Bs + i * 4096 + w * 1024);
  }
  __syncthreads();
#pragma unroll
  for (int kk = 0; kk < 2; ++kk) {
    const int cb = kk * 64 + ks * 16;
    bf8v av[4], bv[4];
#pragma unroll
    for (int m = 0; m < 4; ++m) av[m] = ldfrag(As, wr + m * 16 + fr, cb);
#pragma unroll
    for (int n = 0; n < 4; ++n) bv[n] = ldfrag(Bs, wc + n * 16 + fr, cb);
#pragma unroll
    for (int m = 0; m < 4; ++m)
#pragma unroll
      for (int n = 0; n < 4; ++n) acc[m][n] = MFMA16(av[m], bv[n], acc[m][n]);
  }
  const int fq = lane >> 4;
#pragma unroll
  for (int m = 0; m < 4; ++m)
#pragma unroll
    for (int n = 0; n < 4; ++n)
#pragma unroll
      for (int j = 0; j < 4; ++j) {
        int rg = bm + wr + m * 16 + fq * 4 + j;          // token 0..8191
        int col = bn + wc + n * 16 + fr;                 // feature 0..255
        int b = rg >> 11, l = rg & 2047;
        float v = fmaxf(RATIO * acc[m][n][j], 0.f) + STABC;
        out[(((size_t)(b * H_ + h)) * L_ + l) * M_ + col] = f2bf(v);
      }
}

// ---------------- transpose Vh[tok][512] head-slices -> VT[bh][64][2048] ----------------
__global__ __launch_bounds__(256) void vt_k(const ushort_t* __restrict__ Vh, ushort_t* __restrict__ VT) {
  __shared__ ushort_t Ls[256][72];
  const int lt = blockIdx.x, bh = blockIdx.y, b = bh >> 3, h = bh & 7;
  const int tid = threadIdx.x, l0 = lt * 256;
#pragma unroll
  for (int i = 0; i < 8; ++i) {
    int e = tid + i * 256, l = e >> 3, d8 = e & 7;
    *(uint4*)&Ls[l][d8 * 8] = *(const uint4*)&Vh[(size_t)(b * L_ + l0 + l) * DIM_ + h * 64 + d8 * 8];
  }
  __syncthreads();
#pragma unroll
  for (int i = 0; i < 8; ++i) {
    int e = tid + i * 256, d = e >> 5, lc = e & 31;
    union { ushort_t u[8]; uint4 v; } o;
#pragma unroll
    for (int q = 0; q < 8; ++q) o.u[q] = Ls[lc * 8 + q][d];
    *(uint4*)&VT[((size_t)(bh * 64 + d)) * L_ + l0 + lc * 8] = o.v;
  }
}

// ---------------- transpose kp[bh][2048][256] -> kpT[bh][256][2048] ----------------
__global__ __launch_bounds__(256) void trkp_k(const ushort_t* __restrict__ kp, ushort_t* __restrict__ kpT) {
  __shared__ ushort_t Ls[64][264];
  const int lt = blockIdx.x, bh = blockIdx.y;
  const int tid = threadIdx.x, l0 = lt * 64;
#pragma unroll
  for (int i = 0; i < 8; ++i) {
    int e = tid + i * 256, l = e >> 5, m8 = e & 31;
    *(uint4*)&Ls[l][m8 * 8] = *(const uint4*)&kp[((size_t)bh * L_ + l0 + l) * M_ + m8 * 8];
  }
  __syncthreads();
#pragma unroll
  for (int i = 0; i < 8; ++i) {
    int e = tid + i * 256, m = e >> 3, lc = e & 7;
    union { ushort_t u[8]; uint4 v; } o;
#pragma unroll
    for (int q = 0; q < 8; ++q) o.u[q] = Ls[lc * 8 + q][m];
    *(uint4*)&kpT[((size_t)bh * M_ + m)* L_ + l0 + lc * 8] = o.v;
  }
}

// ---------------- per-chunk partials: S[bh][ci][d:0..63]=VT@kpT^T, row 64 = sum kp (ones trick) ----------------
__global__ __launch_bounds__(256) void cp_k(const ushort_t* __restrict__ VT, const ushort_t* __restrict__ kpT,
                                            ushort_t* __restrict__ S) {
  __shared__ ushort_t As[80 * 64];    // rows 0-63 = VT, 64 = ones, 65-79 garbage
  __shared__ ushort_t Bs[256 * 64];   // kpT rows (m)
  const int ci = blockIdx.x, bh = blockIdx.y;
  const int tid = threadIdx.x, lane = tid & 63, w = tid >> 6;
  const int srow = w * 8 + (lane >> 3);
  const int scol = (((lane & 7) * 16) ^ ((lane >> 3) << 4)) >> 1;
  const int fr = lane & 15, ks = lane >> 4;
  f4v acc[5][4] = {};
  if (tid < 32) ((uint32_t*)As)[2048 + tid] = 0x3f803f80u;   // ones row 64
  for (int kt = 0; kt < 2; ++kt) {
    const int kb = ci * CHK + kt * 64;
#pragma unroll
    for (int i = 0; i < 2; ++i) {
      int r = i * 32 + srow;
      gll16(VT + ((size_t)bh * 64 + r) * L_ + kb + scol, (char*)As + i * 4096 + w * 1024);
    }
#pragma unroll
    for (int i = 0; i < 8; ++i) {
      int r = i * 32 + srow;
      gll16(kpT + ((size_t)bh * M_ + r) * L_ + kb + scol, (char*)Bs + i * 4096 + w * 1024);
    }
    __syncthreads();
#pragma unroll
    for (int kk = 0; kk < 2; ++kk) {
      const int cb = kk * 64 + ks * 16;
      bf8v av[5], bv[4];
#pragma unroll
      for (int m = 0; m < 5; ++m) av[m] = ldfrag(As, m * 16 + fr, cb);
#pragma unroll
      for (int n = 0; n < 4; ++n) bv[n] = ldfrag(Bs, w * 64 + n * 16 + fr, cb);
#pragma unroll
      for (int m = 0; m < 5; ++m)
#pragma unroll
        for (int n = 0; n < 4; ++n) acc[m][n] = MFMA16(av[m], bv[n], acc[m][n]);
    }
    __syncthreads();
  }
  const int fq = lane >> 4;
  const size_t base = ((size_t)bh * NC + ci) * 65;
#pragma unroll
  for (int m = 0; m < 5; ++m)
#pragma unroll
    for (int n = 0; n < 4; ++n)
#pragma unroll
      for (int j = 0; j < 4; ++j) {
        int row = m * 16 + fq * 4 + j;
        if (row < 65) {
          int col = w * 64 + n * 16 + fr;
          S[(base + row) * M_ + col] = f2bf(acc[m][n][j]);
        }
      }
}

// ---------------- in-place exclusive prefix over chunks (rows incl. sk row 64) ----------------
__global__ __launch_bounds__(256) void prefix_k(ushort_t* __restrict__ S) {
  const int r = blockIdx.x, bh = blockIdx.y, m = threadIdx.x;
  ushort_t* p = S + (((size_t)bh * NC) * 65 + r) * M_ + m;
  float carry = 0.f;
  for (int ci = 0; ci < NC; ++ci) {
    ushort_t* q = p + (size_t)ci * 65 * M_;
    float t = bf2f(*q);
    *q = f2bf(carry);
    carry += t;
  }
}

// ---------------- A_c = causal-masked qp @ kp^T within chunk -> bf16 ----------------
__global__ __launch_bounds__(256) void qk_k(const ushort_t* __restrict__ qp, const ushort_t* __restrict__ kp,
                                            ushort_t* __restrict__ Ac) {
  __shared__ ushort_t As[128 * 64];
  __shared__ ushort_t Bs[128 * 64];
  const int ci = blockIdx.x, bh = blockIdx.y;
  const int tid = threadIdx.x, lane = tid & 63, w = tid >> 6;
  const int srow = w * 8 + (lane >> 3);
  const int scol = (((lane & 7) * 16) ^ ((lane >> 3) << 4)) >> 1;
  const int wr = (w >> 1) * 64, wc = (w & 1) * 64;
  const int fr = lane & 15, ks = lane >> 4;
  const size_t rowb = (size_t)bh * L_ + ci * CHK;
  f4v acc[4][4] = {};
  for (int kt = 0; kt < 4; ++kt) {
#pragma unroll
    for (int i = 0; i < 4; ++i) {
      int r = i * 32 + srow;
      gll16(qp + (rowb + r) * M_ + kt * 64 + scol, (char*)As + i * 4096 + w * 1024);
      gll16(kp + (rowb + r) * M_ + kt * 64 + scol, (char*)Bs + i * 4096 + w * 1024);
    }
    __syncthreads();
#pragma unroll
    for (int kk = 0; kk < 2; ++kk) {
      const int cb = kk * 64 + ks * 16;
      bf8v av[4], bv[4];
#pragma unroll
      for (int m = 0; m < 4; ++m) av[m] = ldfrag(As, wr + m * 16 + fr, cb);
#pragma unroll
      for (int n = 0; n < 4; ++n) bv[n] = ldfrag(Bs, wc + n * 16 + fr, cb);
#pragma unroll
      for (int m = 0; m < 4; ++m)
#pragma unroll
        for (int n = 0; n < 4; ++n) acc[m][n] = MFMA16(av[m], bv[n], acc[m][n]);
    }
    __syncthreads();
  }
  const int fq = lane >> 4;
#pragma unroll
  for (int m = 0; m < 4; ++m)
#pragma unroll
    for (int n = 0; n < 4; ++n)
#pragma unroll
      for (int j = 0; j < 4; ++j) {
        int row = wr + m * 16 + fq * 4 + j;
        int col = wc + n * 16 + fr;
        float v = (col <= row) ? acc[m][n][j] : 0.f;
        Ac[(rowb + row) * CHK + col] = f2bf(v);
      }
}

// ---------------- out: [A_c | qp] @ [[VT;ones] ; [S;sk]] with den = col 64; attn bf16 ----------------
__global__ __launch_bounds__(256) void outk_k(const ushort_t* __restrict__ Ac, const ushort_t* __restrict__ qp,
                                              const ushort_t* __restrict__ VT, const ushort_t* __restrict__ S,
                                              ushort_t* __restrict__ attn) {
  __shared__ ushort_t As[128 * 64];
  __shared__ ushort_t Bs[80 * 64];    // rows 0-63 = V^T/S^T slice, 64 = ones/sk, 65-79 garbage
  const int ci = blockIdx.x, bh = blockIdx.y;
  const int tid = threadIdx.x, lane = tid & 63, w = tid >> 6;
  const int srow = w * 8 + (lane >> 3);
  const int scol = (((lane & 7) * 16) ^ ((lane >> 3) << 4)) >> 1;
  const int fr = lane & 15, ks = lane >> 4;
  const size_t rowb = (size_t)bh * L_ + ci * CHK;
  const size_t sbase = ((size_t)bh * NC + ci) * 65;
  f4v acc[2][5] = {};
  for (int kt = 0; kt < 6; ++kt) {
#pragma unroll
    for (int i = 0; i < 4; ++i) {
      int r = i * 32 + srow;
      const ushort_t* ga = (kt < 2) ? (Ac + (rowb + r) * CHK + kt * 64 + scol)
                                    : (qp + (rowb + r) * M_ + (kt - 2) * 64 + scol);
      gll16(ga, (char*)As + i * 4096 + w * 1024);
    }
#pragma unroll
    for (int i = 0; i < 2; ++i) {
      int r = i * 32 + srow;
      const ushort_t* gb = (kt < 2) ? (VT + ((size_t)bh * 64 + r) * L_ + ci * CHK + kt * 64 + scol)
                                    : (S + (sbase + r) * M_ + (kt - 2) * 64 + scol);
      gll16(gb, (char*)Bs + i * 4096 + w * 1024);
    }
    if (tid < 32) {
      uint32_t vv = (kt < 2) ? 0x3f803f80u
                             : ((const uint32_t*)(S + (sbase + 64) * M_ + (kt - 2) * 64))[tid];
      ((uint32_t*)Bs)[2048 + tid] = vv;   // row 64
    }
    __syncthreads();
#pragma unroll
    for (int kk = 0; kk < 2; ++kk) {
      const int cb = kk * 64 + ks * 16;
      bf8v av[2], bv[5];
#pragma unroll
      for (int m = 0; m < 2; ++m) av[m] = ldfrag(As, w * 32 + m * 16 + fr, cb);
#pragma unroll
      for (int n = 0; n < 5; ++n) bv[n] = ldfrag(Bs, n * 16 + fr, cb);
#pragma unroll
      for (int m = 0; m < 2; ++m)
#pragma unroll
        for (int n = 0; n < 5; ++n) acc[m][n] = MFMA16(av[m], bv[n], acc[m][n]);
    }
    __syncthreads();
  }
  const int fq = lane >> 4;
  const int b = bh >> 3, h = bh & 7;
#pragma unroll
  for (int m = 0; m < 2; ++m) {
    float dinv[4];
#pragma unroll
    for (int j = 0; j < 4; ++j) {
      float den = __shfl(acc[m][4][j], (lane & 48));   // col 64 lives at fr==0
      dinv[j] = 1.f / den;
    }
#pragma unroll
    for (int n = 0; n < 4; ++n)
#pragma unroll
      for (int j = 0; j < 4; ++j) {
        int l = ci * CHK + w * 32 + m * 16 + fq * 4 + j;
        int col = h * 64 + n * 16 + fr;
        attn[((size_t)(b * L_ + l)) * DIM_ + col] = f2bf(acc[m][n][j] * dinv[j]);
      }
  }
}

extern "C" void kernel_launch(void* const* d_in, const int* in_sizes, int n_in,
                              void* d_out, int out_size, void* d_ws, size_t ws_size,
                              hipStream_t stream) {
  const float* query = (const float*)d_in[0];
  const float* key   = (const float*)d_in[1];
  const float* value = (const float*)d_in[2];
  const float* proj  = (const float*)d_in[3];
  const float* wq = (const float*)d_in[4];
  const float* bq = (const float*)d_in[5];
  const float* wk = (const float*)d_in[6];
  const float* bk = (const float*)d_in[7];
  const float* wv = (const float*)d_in[8];
  const float* bv = (const float*)d_in[9];
  const float* wo = (const float*)d_in[10];
  const float* bo = (const float*)d_in[11];

  char* ws = (char*)d_ws;
  ushort_t* Wc   = (ushort_t*)(ws);                 // wq,wk,wv,wo (512K elems ea) + proj: 2,129,920 B
  ushort_t* Xc   = (ushort_t*)(ws + 2129920);       // 8 MB   (bf16 of current raw input)
  ushort_t* XH   = (ushort_t*)(ws + 10518528);      // 8 MB   (projected head buffer; later attn)
  ushort_t* VT   = (ushort_t*)(ws + 18907136);      // 8 MB   [bh][64][2048]
  ushort_t* qp   = (ushort_t*)(ws + 27295744);      // 32 MB  [bh][2048][256]
  ushort_t* kp   = (ushort_t*)(ws + 60850176);      // 32 MB
  ushort_t* kpT  = (ushort_t*)(ws + 94404608);      // 32 MB  [bh][256][2048]; A_c reuses this after cp_k
  ushort_t* Ac   = (ushort_t*)(ws + 94404608);      // 16 MB  [bh][2048][128]
  ushort_t* Skv  = (ushort_t*)(ws + 127959040);     // 16.25 MB [bh][16][65][256]
  const ushort_t* Wq = Wc;
  const ushort_t* Wk = Wc + 262144;
  const ushort_t* Wv = Wc + 524288;
  const ushort_t* Wo = Wc + 786432;
  const ushort_t* Pc = Wc + 1048576;

  dim3 blk(256);
  cvt_w_k<<<520, blk, 0, stream>>>(wq, wk, wv, wo, proj, Wc);
  // V pipeline first so XH can be reused
  cvt_k<<<2048, blk, 0, stream>>>(value, Xc);
  gemm512_k<1><<<dim3(64, 4), blk, 0, stream>>>(Xc, Wv, bv, XH);
  vt_k<<<dim3(8, BH), blk, 0, stream>>>(XH, VT);
  // Q
  cvt_k<<<2048, blk, 0, stream>>>(query, Xc);
  gemm512_k<1><<<dim3(64, 4), blk, 0, stream>>>(Xc, Wq, bq, XH);
  feat_k<<<dim3(64, 2, 8), blk, 0, stream>>>(XH, Pc, qp);
  // K
  cvt_k<<<2048, blk, 0, stream>>>(key, Xc);
  gemm512_k<1><<<dim3(64, 4), blk, 0, stream>>>(Xc, Wk, bk, XH);
  feat_k<<<dim3(64, 2, 8), blk, 0, stream>>>(XH, Pc, kp);
  trkp_k<<<dim3(32, BH), blk, 0, stream>>>(kp, kpT);
  cp_k<<<dim3(NC, BH), blk, 0, stream>>>(VT, kpT, Skv);
  prefix_k<<<dim3(65, BH), blk, 0, stream>>>(Skv);
  qk_k<<<dim3(NC, BH), blk, 0, stream>>>(qp, kp, Ac);
  outk_k<<<dim3(NC, BH), blk, 0, stream>>>(Ac, qp, VT, Skv, XH);
  gemm512_k<0><<<dim3(64, 4), blk, 0, stream>>>(XH, Wo, bo, (float*)d_out);
}

// Round 3
// 127.411 us; speedup vs baseline: 5.0632x; 1.3036x over previous
//
#include <hip/hip_runtime.h>
#include <stdint.h>

#define B_ 4
#define L_ 2048
#define H_ 8
#define DK 64
#define M_ 256
#define DIM_ 512
#define NTOK (B_ * L_)
#define CHK 128
#define NC (L_ / CHK)
#define BH (B_ * H_)
#define RATIO 0.0625f
#define STABC 1e-5f

typedef unsigned short ushort_t;
typedef __attribute__((ext_vector_type(8))) short bf8v;   // 8 bf16 = 4 VGPR
typedef __attribute__((ext_vector_type(4))) float f4v;    // MFMA accumulator

#define MFMA16(a, b, c) __builtin_amdgcn_mfma_f32_16x16x32_bf16(a, b, c, 0, 0, 0)

__device__ __forceinline__ ushort_t f2bf(float f) {
  uint32_t u = __float_as_uint(f);
  return (ushort_t)((u + 0x7fffu + ((u >> 16) & 1u)) >> 16);
}
__device__ __forceinline__ float bf2f(ushort_t u) { return __uint_as_float(((uint32_t)u) << 16); }

__device__ __forceinline__ void gll16(const void* g, void* l) {
  __builtin_amdgcn_global_load_lds((const __attribute__((address_space(1))) void*)g,
                                   (__attribute__((address_space(3))) void*)l, 16, 0, 0);
}

// LDS tile row stride 128 B, XOR-swizzled: byte = row*128 + (cb ^ ((row&7)<<4))
__device__ __forceinline__ bf8v ldfrag(const ushort_t* base, int row, int cb) {
  return *(const bf8v*)((const char*)base + row * 128 + (cb ^ ((row & 7) << 4)));
}

// ---------------- one-shot bf16 convert of q,k,v,weights,proj ----------------
__global__ __launch_bounds__(256) void cvt_all(const float* __restrict__ q, const float* __restrict__ k,
                                               const float* __restrict__ v, const float* __restrict__ wq,
                                               const float* __restrict__ wk, const float* __restrict__ wv,
                                               const float* __restrict__ wo, const float* __restrict__ pj,
                                               ushort_t* __restrict__ Xq, ushort_t* __restrict__ Xk,
                                               ushort_t* __restrict__ Xv, ushort_t* __restrict__ Wc) {
  int i = (blockIdx.x * 256 + threadIdx.x) * 8;
  const float* s;
  ushort_t* d;
  int soff, doff;
  if (i < 4194304)       { s = q;  d = Xq; soff = i;            doff = soff; }
  else if (i < 8388608)  { s = k;  d = Xk; soff = i - 4194304;  doff = soff; }
  else if (i < 12582912) { s = v;  d = Xv; soff = i - 8388608;  doff = soff; }
  else {
    int j = i - 12582912;
    d = Wc; doff = j;
    if (j < 262144)       { s = wq; soff = j; }
    else if (j < 524288)  { s = wk; soff = j - 262144; }
    else if (j < 786432)  { s = wv; soff = j - 524288; }
    else if (j < 1048576) { s = wo; soff = j - 786432; }
    else                  { s = pj; soff = j - 1048576; }
  }
  float4 a = *(const float4*)(s + soff);
  float4 b = *(const float4*)(s + soff + 4);
  union { ushort_t u[8]; uint4 vv; } o;
  o.u[0] = f2bf(a.x); o.u[1] = f2bf(a.y); o.u[2] = f2bf(a.z); o.u[3] = f2bf(a.w);
  o.u[4] = f2bf(b.x); o.u[5] = f2bf(b.y); o.u[6] = f2bf(b.z); o.u[7] = f2bf(b.w);
  *(uint4*)(d + doff) = o.vv;
}

// ---------------- Y[8192,512] = X @ W^T + bias; BM=128, BN=64 (grid 64x8) ----------------
// OUTMODE: 0 = fp32 Y, 1 = bf16 Y, 2 = V-path: transpose head-slice -> VT[bh][64][2048]
template <int OUTMODE>
__global__ __launch_bounds__(256) void gemm512b(const ushort_t* __restrict__ A, const ushort_t* __restrict__ Bw,
                                                const float* __restrict__ bias, void* __restrict__ Y,
                                                ushort_t* __restrict__ VT) {
  __shared__ ushort_t As[128 * 64];
  __shared__ ushort_t Bs[64 * 64];
  const int tid = threadIdx.x, lane = tid & 63, w = tid >> 6;
  const int bm = blockIdx.x * 128, bn = blockIdx.y * 64;
  const int srow = w * 8 + (lane >> 3);
  const int scol = (((lane & 7) * 16) ^ ((lane >> 3) << 4)) >> 1;
  const int wr = (w >> 1) * 64, wc = (w & 1) * 32;
  const int fr = lane & 15, ks = lane >> 4, fq = lane >> 4;
  f4v acc[4][2] = {};
  for (int k0 = 0; k0 < DIM_; k0 += 64) {
#pragma unroll
    for (int i = 0; i < 4; ++i)
      gll16(A + (size_t)(bm + i * 32 + srow) * DIM_ + k0 + scol, (char*)As + i * 4096 + w * 1024);
#pragma unroll
    for (int i = 0; i < 2; ++i)
      gll16(Bw + (size_t)(bn + i * 32 + srow) * DIM_ + k0 + scol, (char*)Bs + i * 4096 + w * 1024);
    __syncthreads();
#pragma unroll
    for (int kk = 0; kk < 2; ++kk) {
      const int cb = kk * 64 + ks * 16;
      bf8v av[4], bv[2];
#pragma unroll
      for (int m = 0; m < 4; ++m) av[m] = ldfrag(As, wr + m * 16 + fr, cb);
#pragma unroll
      for (int n = 0; n < 2; ++n) bv[n] = ldfrag(Bs, wc + n * 16 + fr, cb);
#pragma unroll
      for (int m = 0; m < 4; ++m)
#pragma unroll
        for (int n = 0; n < 2; ++n) acc[m][n] = MFMA16(av[m], bv[n], acc[m][n]);
    }
    __syncthreads();
  }
  if constexpr (OUTMODE == 2) {
    __shared__ ushort_t Tt[64 * 136];   // [dim][token], stride 136 keeps 16B-aligned rows
#pragma unroll
    for (int m = 0; m < 4; ++m)
#pragma unroll
      for (int n = 0; n < 2; ++n) {
        int cl = wc + n * 16 + fr;
        float bsv = bias[bn + cl];
#pragma unroll
        for (int j = 0; j < 4; ++j) {
          int rl = wr + m * 16 + fq * 4 + j;
          Tt[cl * 136 + rl] = f2bf(acc[m][n][j] + bsv);
        }
      }
    __syncthreads();
    const int d = tid >> 2, seg = tid & 3;
    const int b = bm >> 11, h = blockIdx.y, l0 = bm & 2047;
    size_t vbase = ((size_t)((b * 8 + h) * 64 + d)) * L_ + l0 + seg * 32;
#pragma unroll
    for (int q = 0; q < 4; ++q)
      *(uint4*)&VT[vbase + q * 8] = *(const uint4*)&Tt[d * 136 + seg * 32 + q * 8];
  } else {
#pragma unroll
    for (int m = 0; m < 4; ++m)
#pragma unroll
      for (int n = 0; n < 2; ++n) {
        int col = bn + wc + n * 16 + fr;
        float bsv = bias[col];
#pragma unroll
        for (int j = 0; j < 4; ++j) {
          int row = bm + wr + m * 16 + fq * 4 + j;
          float v = acc[m][n][j] + bsv;
          if (OUTMODE) ((ushort_t*)Y)[(size_t)row * DIM_ + col] = f2bf(v);
          else ((float*)Y)[(size_t)row * DIM_ + col] = v;
        }
      }
  }
}

// ---------------- phi = relu(RATIO * X_head @ proj^T)+STAB -> kp/qp; TR=1 also writes kpT ----------------
template <int TR>
__global__ __launch_bounds__(256) void feat_k(const ushort_t* __restrict__ X, const ushort_t* __restrict__ P,
                                              ushort_t* __restrict__ out, ushort_t* __restrict__ outT) {
  __shared__ ushort_t As[128 * 64];
  __shared__ ushort_t Bs[128 * 64];
  const int tid = threadIdx.x, lane = tid & 63, w = tid >> 6;
  const int bm = blockIdx.x * 128, bn = blockIdx.y * 128, h = blockIdx.z;
  const int srow = w * 8 + (lane >> 3);
  const int scol = (((lane & 7) * 16) ^ ((lane >> 3) << 4)) >> 1;
  const int wr = (w >> 1) * 64, wc = (w & 1) * 64;
  const int fr = lane & 15, ks = lane >> 4, fq = lane >> 4;
  f4v acc[4][4] = {};
#pragma unroll
  for (int i = 0; i < 4; ++i) {
    int r = i * 32 + srow;
    gll16(X + (size_t)(bm + r) * DIM_ + h * 64 + scol, (char*)As + i * 4096 + w * 1024);
    gll16(P + (size_t)(bn + r) * 64 + scol, (char*)Bs + i * 4096 + w * 1024);
  }
  __syncthreads();
#pragma unroll
  for (int kk = 0; kk < 2; ++kk) {
    const int cb = kk * 64 + ks * 16;
    bf8v av[4], bv[4];
#pragma unroll
    for (int m = 0; m < 4; ++m) av[m] = ldfrag(As, wr + m * 16 + fr, cb);
#pragma unroll
    for (int n = 0; n < 4; ++n) bv[n] = ldfrag(Bs, wc + n * 16 + fr, cb);
#pragma unroll
    for (int m = 0; m < 4; ++m)
#pragma unroll
      for (int n = 0; n < 4; ++n) acc[m][n] = MFMA16(av[m], bv[n], acc[m][n]);
  }
  const int b = bm >> 11, l0 = bm & 2047;
  const int bh = b * H_ + h;
  if constexpr (TR == 0) {
#pragma unroll
    for (int m = 0; m < 4; ++m)
#pragma unroll
      for (int n = 0; n < 4; ++n)
#pragma unroll
        for (int j = 0; j < 4; ++j) {
          int rl = wr + m * 16 + fq * 4 + j;
          int col = bn + wc + n * 16 + fr;
          float v = fmaxf(RATIO * acc[m][n][j], 0.f) + STABC;
          out[((size_t)bh * L_ + l0 + rl) * M_ + col] = f2bf(v);
        }
  } else {
    __shared__ ushort_t Tt[128 * 136];   // [feature][token]
#pragma unroll
    for (int m = 0; m < 4; ++m)
#pragma unroll
      for (int n = 0; n < 4; ++n)
#pragma unroll
        for (int j = 0; j < 4; ++j) {
          int rl = wr + m * 16 + fq * 4 + j;
          int cl = wc + n * 16 + fr;
          float v = fmaxf(RATIO * acc[m][n][j], 0.f) + STABC;
          ushort_t bv_ = f2bf(v);
          out[((size_t)bh * L_ + l0 + rl) * M_ + bn + cl] = bv_;
          Tt[cl * 136 + rl] = bv_;
        }
    __syncthreads();
    const int ml = tid >> 1, seg = tid & 1;
    size_t tb = ((size_t)bh * M_ + bn + ml) * L_ + l0 + seg * 64;
#pragma unroll
    for (int q = 0; q < 8; ++q)
      *(uint4*)&outT[tb + q * 8] = *(const uint4*)&Tt[ml * 136 + seg * 64 + q * 8];
  }
}

// ---------------- per-chunk partials: S[d 0..63][m] = VT@kpT^T, row 64 = sum kp ----------------
__global__ __launch_bounds__(256) void cp_k(const ushort_t* __restrict__ VT, const ushort_t* __restrict__ kpT,
                                            ushort_t* __restrict__ S) {
  __shared__ ushort_t As[80 * 64];
  __shared__ ushort_t Bs[256 * 64];
  const int ci = blockIdx.x, bh = blockIdx.y;
  const int tid = threadIdx.x, lane = tid & 63, w = tid >> 6;
  const int srow = w * 8 + (lane >> 3);
  const int scol = (((lane & 7) * 16) ^ ((lane >> 3) << 4)) >> 1;
  const int fr = lane & 15, ks = lane >> 4;
  f4v acc[5][4] = {};
  if (tid < 32) ((uint32_t*)As)[2048 + tid] = 0x3f803f80u;   // ones row 64
  for (int kt = 0; kt < 2; ++kt) {
    const int kb = ci * CHK + kt * 64;
#pragma unroll
    for (int i = 0; i < 2; ++i)
      gll16(VT + ((size_t)bh * 64 + i * 32 + srow) * L_ + kb + scol, (char*)As + i * 4096 + w * 1024);
#pragma unroll
    for (int i = 0; i < 8; ++i)
      gll16(kpT + ((size_t)bh * M_ + i * 32 + srow) * L_ + kb + scol, (char*)Bs + i * 4096 + w * 1024);
    __syncthreads();
#pragma unroll
    for (int kk = 0; kk < 2; ++kk) {
      const int cb = kk * 64 + ks * 16;
      bf8v av[5], bv[4];
#pragma unroll
      for (int m = 0; m < 5; ++m) av[m] = ldfrag(As, m * 16 + fr, cb);
#pragma unroll
      for (int n = 0; n < 4; ++n) bv[n] = ldfrag(Bs, w * 64 + n * 16 + fr, cb);
#pragma unroll
      for (int m = 0; m < 5; ++m)
#pragma unroll
        for (int n = 0; n < 4; ++n) acc[m][n] = MFMA16(av[m], bv[n], acc[m][n]);
    }
    __syncthreads();
  }
  const int fq = lane >> 4;
  const size_t base = ((size_t)bh * NC + ci) * 65;
#pragma unroll
  for (int m = 0; m < 5; ++m)
#pragma unroll
    for (int n = 0; n < 4; ++n)
#pragma unroll
      for (int j = 0; j < 4; ++j) {
        int row = m * 16 + fq * 4 + j;
        if (row < 65) S[(base + row) * M_ + w * 64 + n * 16 + fr] = f2bf(acc[m][n][j]);
      }
}

// ---------------- exclusive prefix over chunks, vectorized, parallel loads ----------------
__global__ __launch_bounds__(256) void prefix2_k(ushort_t* __restrict__ S) {
  const int g = blockIdx.x * 256 + threadIdx.x;   // 66560 = 32 bh * 2080 uint4-cols
  const int bh = g / 2080, r = g - bh * 2080;
  ushort_t* base = S + (size_t)bh * (NC * 65 * M_) + (size_t)r * 8;
  uint4 v[16];
#pragma unroll
  for (int ci = 0; ci < NC; ++ci) v[ci] = *(const uint4*)(base + (size_t)ci * (65 * M_));
  float c[8] = {};
#pragma unroll
  for (int ci = 0; ci < NC; ++ci) {
    union { uint4 u; ushort_t s[8]; } in, out;
    in.u = v[ci];
#pragma unroll
    for (int e = 0; e < 8; ++e) {
      float t = bf2f(in.s[e]);
      out.s[e] = f2bf(c[e]);
      c[e] += t;
    }
    *(uint4*)(base + (size_t)ci * (65 * M_)) = out.u;
  }
}

// ---------------- fused: A = mask(qp@kp^T) in LDS; out = [A|qp]@[[VT;1];[S;sk]]; attn bf16 ----------------
__global__ __launch_bounds__(256) void qkout_k(const ushort_t* __restrict__ qp, const ushort_t* __restrict__ kp,
                                               const ushort_t* __restrict__ VT, const ushort_t* __restrict__ S,
                                               ushort_t* __restrict__ attn) {
  __shared__ ushort_t As[128 * 64];
  __shared__ ushort_t Bs[128 * 64];
  __shared__ ushort_t At[128 * 128];   // swizzled A-tile, 256 B rows
  const int ci = blockIdx.x, bh = blockIdx.y;
  const int tid = threadIdx.x, lane = tid & 63, w = tid >> 6;
  const int srow = w * 8 + (lane >> 3);
  const int scol = (((lane & 7) * 16) ^ ((lane >> 3) << 4)) >> 1;
  const int fr = lane & 15, ks = lane >> 4, fq = lane >> 4;
  const size_t rowb = (size_t)bh * L_ + ci * CHK;
  // phase 1: QK^T
  {
    const int wr = (w >> 1) * 64, wc = (w & 1) * 64;
    f4v acc[4][4] = {};
    for (int kt = 0; kt < 4; ++kt) {
#pragma unroll
      for (int i = 0; i < 4; ++i) {
        int r = i * 32 + srow;
        gll16(qp + (rowb + r) * M_ + kt * 64 + scol, (char*)As + i * 4096 + w * 1024);
        gll16(kp + (rowb + r) * M_ + kt * 64 + scol, (char*)Bs + i * 4096 + w * 1024);
      }
      __syncthreads();
#pragma unroll
      for (int kk = 0; kk < 2; ++kk) {
        const int cb = kk * 64 + ks * 16;
        bf8v av[4], bv[4];
#pragma unroll
        for (int m = 0; m < 4; ++m) av[m] = ldfrag(As, wr + m * 16 + fr, cb);
#pragma unroll
        for (int n = 0; n < 4; ++n) bv[n] = ldfrag(Bs, wc + n * 16 + fr, cb);
#pragma unroll
        for (int m = 0; m < 4; ++m)
#pragma unroll
          for (int n = 0; n < 4; ++n) acc[m][n] = MFMA16(av[m], bv[n], acc[m][n]);
      }
      __syncthreads();
    }
    // phase 2: masked A -> At (swizzled bf16)
#pragma unroll
    for (int m = 0; m < 4; ++m)
#pragma unroll
      for (int n = 0; n < 4; ++n)
#pragma unroll
        for (int j = 0; j < 4; ++j) {
          int row = wr + m * 16 + fq * 4 + j;
          int col = wc + n * 16 + fr;
          float v = (col <= row) ? acc[m][n][j] : 0.f;
          *(ushort_t*)((char*)At + row * 256 + ((col * 2) ^ ((row & 7) << 4))) = f2bf(v);
        }
  }
  __syncthreads();
  // phase 3: [A | qp] @ [[VT; ones]; [S; sk]]
  const size_t sbase = ((size_t)bh * NC + ci) * 65;
  f4v acc2[2][5] = {};
  for (int kt2 = 0; kt2 < 6; ++kt2) {
    if (kt2 >= 2) {
#pragma unroll
      for (int i = 0; i < 4; ++i)
        gll16(qp + (rowb + i * 32 + srow) * M_ + (kt2 - 2) * 64 + scol, (char*)As + i * 4096 + w * 1024);
    }
#pragma unroll
    for (int i = 0; i < 2; ++i) {
      int r = i * 32 + srow;
      const ushort_t* gb = (kt2 < 2) ? (VT + ((size_t)bh * 64 + r) * L_ + ci * CHK + kt2 * 64 + scol)
                                     : (S + (sbase + r) * M_ + (kt2 - 2) * 64 + scol);
      gll16(gb, (char*)Bs + i * 4096 + w * 1024);
    }
    if (tid < 32)
      ((uint32_t*)Bs)[2048 + tid] = (kt2 < 2) ? 0x3f803f80u
                                              : ((const uint32_t*)(S + (sbase + 64) * M_ + (kt2 - 2) * 64))[tid];
    __syncthreads();
#pragma unroll
    for (int kk = 0; kk < 2; ++kk) {
      const int cb = kk * 64 + ks * 16;
      bf8v av2[2], bv[5];
#pragma unroll
      for (int m = 0; m < 2; ++m) {
        int row = w * 32 + m * 16 + fr;
        if (kt2 < 2)
          av2[m] = *(const bf8v*)((const char*)At + row * 256 + ((kt2 * 128 + cb) ^ ((row & 7) << 4)));
        else
          av2[m] = ldfrag(As, row, cb);
      }
#pragma unroll
      for (int n = 0; n < 5; ++n) bv[n] = ldfrag(Bs, n * 16 + fr, cb);
#pragma unroll
      for (int m = 0; m < 2; ++m)
#pragma unroll
        for (int n = 0; n < 5; ++n) acc2[m][n] = MFMA16(av2[m], bv[n], acc2[m][n]);
    }
    __syncthreads();
  }
  const int b = bh >> 3, h = bh & 7;
#pragma unroll
  for (int m = 0; m < 2; ++m) {
    float dinv[4];
#pragma unroll
    for (int j = 0; j < 4; ++j) {
      float den = __shfl(acc2[m][4][j], (lane & 48));   // col 64 lives at fr==0
      dinv[j] = 1.f / den;
    }
#pragma unroll
    for (int n = 0; n < 4; ++n)
#pragma unroll
      for (int j = 0; j < 4; ++j) {
        int l = ci * CHK + w * 32 + m * 16 + fq * 4 + j;
        int col = h * 64 + n * 16 + fr;
        attn[((size_t)(b * L_ + l)) * DIM_ + col] = f2bf(acc2[m][n][j] * dinv[j]);
      }
  }
}

extern "C" void kernel_launch(void* const* d_in, const int* in_sizes, int n_in,
                              void* d_out, int out_size, void* d_ws, size_t ws_size,
                              hipStream_t stream) {
  const float* query = (const float*)d_in[0];
  const float* key   = (const float*)d_in[1];
  const float* value = (const float*)d_in[2];
  const float* proj  = (const float*)d_in[3];
  const float* wq = (const float*)d_in[4];
  const float* bq = (const float*)d_in[5];
  const float* wk = (const float*)d_in[6];
  const float* bk = (const float*)d_in[7];
  const float* wv = (const float*)d_in[8];
  const float* bv = (const float*)d_in[9];
  const float* wo = (const float*)d_in[10];
  const float* bo = (const float*)d_in[11];

  char* ws = (char*)d_ws;
  ushort_t* Wc  = (ushort_t*)(ws);                  // wq,wk,wv,wo,proj bf16: 2,129,920 B
  ushort_t* Xq  = (ushort_t*)(ws + 2129920);        // 8 MB
  ushort_t* Xk  = (ushort_t*)(ws + 10518528);       // 8 MB
  ushort_t* Xv  = (ushort_t*)(ws + 18907136);       // 8 MB
  ushort_t* XH  = (ushort_t*)(ws + 27295744);       // 8 MB (projected heads / attn)
  ushort_t* VT  = (ushort_t*)(ws + 35684352);       // 8 MB [bh][64][2048]
  ushort_t* qp  = (ushort_t*)(ws + 44072960);       // 32 MB [bh][2048][256]
  ushort_t* kp  = (ushort_t*)(ws + 77627392);       // 32 MB
  ushort_t* kpT = (ushort_t*)(ws + 111181824);      // 32 MB [bh][256][2048]
  ushort_t* Skv = (ushort_t*)(ws + 144736256);      // 17.04 MB [bh][16][65][256]
  const ushort_t* Wq = Wc;
  const ushort_t* Wk = Wc + 262144;
  const ushort_t* Wv = Wc + 524288;
  const ushort_t* Wo = Wc + 786432;
  const ushort_t* Pc = Wc + 1048576;

  dim3 blk(256);
  cvt_all<<<6664, blk, 0, stream>>>(query, key, value, wq, wk, wv, wo, proj, Xq, Xk, Xv, Wc);
  gemm512b<2><<<dim3(64, 8), blk, 0, stream>>>(Xv, Wv, bv, nullptr, VT);
  gemm512b<1><<<dim3(64, 8), blk, 0, stream>>>(Xq, Wq, bq, XH, nullptr);
  feat_k<0><<<dim3(64, 2, 8), blk, 0, stream>>>(XH, Pc, qp, nullptr);
  gemm512b<1><<<dim3(64, 8), blk, 0, stream>>>(Xk, Wk, bk, XH, nullptr);
  feat_k<1><<<dim3(64, 2, 8), blk, 0, stream>>>(XH, Pc, kp, kpT);
  cp_k<<<dim3(NC, BH), blk, 0, stream>>>(VT, kpT, Skv);
  prefix2_k<<<260, blk, 0, stream>>>(Skv);
  qkout_k<<<dim3(NC, BH), blk, 0, stream>>>(qp, kp, VT, Skv, XH);
  gemm512b<0><<<dim3(64, 8), blk, 0, stream>>>(XH, Wo, bo, (float*)d_out, nullptr);
}

// Round 4
// 120.050 us; speedup vs baseline: 5.3736x; 1.0613x over previous
//
#include <hip/hip_runtime.h>
#include <stdint.h>

#define B_ 4
#define L_ 2048
#define H_ 8
#define DK 64
#define M_ 256
#define DIM_ 512
#define NTOK (B_ * L_)
#define CHK 128
#define NC (L_ / CHK)
#define BH (B_ * H_)
#define RATIO 0.0625f
#define STABC 1e-5f

typedef unsigned short ushort_t;
typedef __attribute__((ext_vector_type(8))) short bf8v;   // 8 bf16 = 4 VGPR
typedef __attribute__((ext_vector_type(4))) float f4v;    // MFMA accumulator

#define MFMA16(a, b, c) __builtin_amdgcn_mfma_f32_16x16x32_bf16(a, b, c, 0, 0, 0)

__device__ __forceinline__ ushort_t f2bf(float f) {
  uint32_t u = __float_as_uint(f);
  return (ushort_t)((u + 0x7fffu + ((u >> 16) & 1u)) >> 16);
}
__device__ __forceinline__ float bf2f(ushort_t u) { return __uint_as_float(((uint32_t)u) << 16); }

__device__ __forceinline__ void gll16(const void* g, void* l) {
  __builtin_amdgcn_global_load_lds((const __attribute__((address_space(1))) void*)g,
                                   (__attribute__((address_space(3))) void*)l, 16, 0, 0);
}

// LDS tile row stride 128 B, XOR-swizzled: byte = row*128 + (cb ^ ((row&7)<<4))
__device__ __forceinline__ bf8v ldfrag(const ushort_t* base, int row, int cb) {
  return *(const bf8v*)((const char*)base + row * 128 + (cb ^ ((row & 7) << 4)));
}
// 256 B-row variant (cb up to 256)
__device__ __forceinline__ bf8v ldfrag256(const ushort_t* base, int row, int cb) {
  return *(const bf8v*)((const char*)base + row * 256 + (cb ^ ((row & 7) << 4)));
}

// ---------------- one-shot bf16 convert of q,k,v,weights,proj ----------------
__global__ __launch_bounds__(256) void cvt_all(const float* __restrict__ q, const float* __restrict__ k,
                                               const float* __restrict__ v, const float* __restrict__ wq,
                                               const float* __restrict__ wk, const float* __restrict__ wv,
                                               const float* __restrict__ wo, const float* __restrict__ pj,
                                               ushort_t* __restrict__ Xq, ushort_t* __restrict__ Xk,
                                               ushort_t* __restrict__ Xv, ushort_t* __restrict__ Wc) {
  int i = (blockIdx.x * 256 + threadIdx.x) * 8;
  const float* s;
  ushort_t* d;
  int soff, doff;
  if (i < 4194304)       { s = q;  d = Xq; soff = i;            doff = soff; }
  else if (i < 8388608)  { s = k;  d = Xk; soff = i - 4194304;  doff = soff; }
  else if (i < 12582912) { s = v;  d = Xv; soff = i - 8388608;  doff = soff; }
  else {
    int j = i - 12582912;
    d = Wc; doff = j;
    if (j < 262144)       { s = wq; soff = j; }
    else if (j < 524288)  { s = wk; soff = j - 262144; }
    else if (j < 786432)  { s = wv; soff = j - 524288; }
    else if (j < 1048576) { s = wo; soff = j - 786432; }
    else                  { s = pj; soff = j - 1048576; }
  }
  float4 a = *(const float4*)(s + soff);
  float4 b = *(const float4*)(s + soff + 4);
  union { ushort_t u[8]; uint4 vv; } o;
  o.u[0] = f2bf(a.x); o.u[1] = f2bf(a.y); o.u[2] = f2bf(a.z); o.u[3] = f2bf(a.w);
  o.u[4] = f2bf(b.x); o.u[5] = f2bf(b.y); o.u[6] = f2bf(b.z); o.u[7] = f2bf(b.w);
  *(uint4*)(d + doff) = o.vv;
}

// ---------------- Y[8192,512] = X @ W^T + bias; BM=128, BN=64 (grid 64x8) ----------------
// OUTMODE: 0 = fp32 Y, 1 = bf16 Y, 2 = V-path: transpose head-slice -> VT[bh][64][2048]
template <int OUTMODE>
__global__ __launch_bounds__(256) void gemm512b(const ushort_t* __restrict__ A, const ushort_t* __restrict__ Bw,
                                                const float* __restrict__ bias, void* __restrict__ Y,
                                                ushort_t* __restrict__ VT) {
  __shared__ ushort_t As[128 * 64];
  __shared__ ushort_t Bs[64 * 64];
  const int tid = threadIdx.x, lane = tid & 63, w = tid >> 6;
  const int bm = blockIdx.x * 128, bn = blockIdx.y * 64;
  const int srow = w * 8 + (lane >> 3);
  const int scol = (((lane & 7) * 16) ^ ((lane >> 3) << 4)) >> 1;
  const int wr = (w >> 1) * 64, wc = (w & 1) * 32;
  const int fr = lane & 15, ks = lane >> 4, fq = lane >> 4;
  f4v acc[4][2] = {};
  for (int k0 = 0; k0 < DIM_; k0 += 64) {
#pragma unroll
    for (int i = 0; i < 4; ++i)
      gll16(A + (size_t)(bm + i * 32 + srow) * DIM_ + k0 + scol, (char*)As + i * 4096 + w * 1024);
#pragma unroll
    for (int i = 0; i < 2; ++i)
      gll16(Bw + (size_t)(bn + i * 32 + srow) * DIM_ + k0 + scol, (char*)Bs + i * 4096 + w * 1024);
    __syncthreads();
#pragma unroll
    for (int kk = 0; kk < 2; ++kk) {
      const int cb = kk * 64 + ks * 16;
      bf8v av[4], bv[2];
#pragma unroll
      for (int m = 0; m < 4; ++m) av[m] = ldfrag(As, wr + m * 16 + fr, cb);
#pragma unroll
      for (int n = 0; n < 2; ++n) bv[n] = ldfrag(Bs, wc + n * 16 + fr, cb);
#pragma unroll
      for (int m = 0; m < 4; ++m)
#pragma unroll
        for (int n = 0; n < 2; ++n) acc[m][n] = MFMA16(av[m], bv[n], acc[m][n]);
    }
    __syncthreads();
  }
  if constexpr (OUTMODE == 2) {
    __shared__ ushort_t Tt[64 * 136];   // [dim][token]
#pragma unroll
    for (int m = 0; m < 4; ++m)
#pragma unroll
      for (int n = 0; n < 2; ++n) {
        int cl = wc + n * 16 + fr;
        float bsv = bias[bn + cl];
#pragma unroll
        for (int j = 0; j < 4; ++j) {
          int rl = wr + m * 16 + fq * 4 + j;
          Tt[cl * 136 + rl] = f2bf(acc[m][n][j] + bsv);
        }
      }
    __syncthreads();
    const int d = tid >> 2, seg = tid & 3;
    const int b = bm >> 11, h = blockIdx.y, l0 = bm & 2047;
    size_t vbase = ((size_t)((b * 8 + h) * 64 + d)) * L_ + l0 + seg * 32;
#pragma unroll
    for (int q = 0; q < 4; ++q)
      *(uint4*)&VT[vbase + q * 8] = *(const uint4*)&Tt[d * 136 + seg * 32 + q * 8];
  } else {
#pragma unroll
    for (int m = 0; m < 4; ++m)
#pragma unroll
      for (int n = 0; n < 2; ++n) {
        int col = bn + wc + n * 16 + fr;
        float bsv = bias[col];
#pragma unroll
        for (int j = 0; j < 4; ++j) {
          int row = bm + wr + m * 16 + fq * 4 + j;
          float v = acc[m][n][j] + bsv;
          if (OUTMODE) ((ushort_t*)Y)[(size_t)row * DIM_ + col] = f2bf(v);
          else ((float*)Y)[(size_t)row * DIM_ + col] = v;
        }
      }
  }
}

// ---------------- qp = relu(RATIO * XHq_head @ proj^T)+STAB -> [bh][L][M] ----------------
__global__ __launch_bounds__(256) void feat_k(const ushort_t* __restrict__ X, const ushort_t* __restrict__ P,
                                              ushort_t* __restrict__ out) {
  __shared__ ushort_t As[128 * 64];
  __shared__ ushort_t Bs[128 * 64];
  const int tid = threadIdx.x, lane = tid & 63, w = tid >> 6;
  const int bm = blockIdx.x * 128, bn = blockIdx.y * 128, h = blockIdx.z;
  const int srow = w * 8 + (lane >> 3);
  const int scol = (((lane & 7) * 16) ^ ((lane >> 3) << 4)) >> 1;
  const int wr = (w >> 1) * 64, wc = (w & 1) * 64;
  const int fr = lane & 15, ks = lane >> 4, fq = lane >> 4;
  f4v acc[4][4] = {};
#pragma unroll
  for (int i = 0; i < 4; ++i) {
    int r = i * 32 + srow;
    gll16(X + (size_t)(bm + r) * DIM_ + h * 64 + scol, (char*)As + i * 4096 + w * 1024);
    gll16(P + (size_t)(bn + r) * 64 + scol, (char*)Bs + i * 4096 + w * 1024);
  }
  __syncthreads();
#pragma unroll
  for (int kk = 0; kk < 2; ++kk) {
    const int cb = kk * 64 + ks * 16;
    bf8v av[4], bv[4];
#pragma unroll
    for (int m = 0; m < 4; ++m) av[m] = ldfrag(As, wr + m * 16 + fr, cb);
#pragma unroll
    for (int n = 0; n < 4; ++n) bv[n] = ldfrag(Bs, wc + n * 16 + fr, cb);
#pragma unroll
    for (int m = 0; m < 4; ++m)
#pragma unroll
      for (int n = 0; n < 4; ++n) acc[m][n] = MFMA16(av[m], bv[n], acc[m][n]);
  }
  const int b = bm >> 11, l0 = bm & 2047;
  const int bh = b * H_ + h;
#pragma unroll
  for (int m = 0; m < 4; ++m)
#pragma unroll
    for (int n = 0; n < 4; ++n)
#pragma unroll
      for (int j = 0; j < 4; ++j) {
        int rl = wr + m * 16 + fq * 4 + j;
        int col = bn + wc + n * 16 + fr;
        float v = fmaxf(RATIO * acc[m][n][j], 0.f) + STABC;
        out[((size_t)bh * L_ + l0 + rl) * M_ + col] = f2bf(v);
      }
}

// ---------------- cp2: fused kp-feature + per-chunk partials ----------------
// kpT[m][l] = relu(RATIO*proj@XHk_chunk^T)+STAB in LDS; kp[l][m] -> global;
// S[d 0..63][m] = VT_chunk @ kpT^T; row 64 = sum_l kp (ones row)
__global__ __launch_bounds__(256) void cp2_k(const ushort_t* __restrict__ XHk, const ushort_t* __restrict__ P,
                                             const ushort_t* __restrict__ VT, ushort_t* __restrict__ kp,
                                             ushort_t* __restrict__ S) {
  __shared__ ushort_t Ps[256 * 64];    // proj, 128B rows swizzled (32 KB)
  __shared__ ushort_t Xs[128 * 64];    // XHk chunk, then [VT;ones] subtiles (16 KB)
  __shared__ ushort_t Kt[256 * 128];   // kpT [m][l], 256B rows swizzled (64 KB)
  const int ci = blockIdx.x, bh = blockIdx.y;
  const int b = bh >> 3, h = bh & 7;
  const int tid = threadIdx.x, lane = tid & 63, w = tid >> 6;
  const int srow = w * 8 + (lane >> 3);
  const int scol = (((lane & 7) * 16) ^ ((lane >> 3) << 4)) >> 1;
  const int fr = lane & 15, ks = lane >> 4, fq = lane >> 4;
  const int l0 = ci * CHK;
#pragma unroll
  for (int i = 0; i < 8; ++i)
    gll16(P + (size_t)(i * 32 + srow) * 64 + scol, (char*)Ps + i * 4096 + w * 1024);
#pragma unroll
  for (int i = 0; i < 4; ++i)
    gll16(XHk + (size_t)(b * L_ + l0 + i * 32 + srow) * DIM_ + h * 64 + scol, (char*)Xs + i * 4096 + w * 1024);
  __syncthreads();
  // feat: C[m][l], wave w owns m-range w*64, all 128 tokens
  {
    f4v acc[4][8] = {};
#pragma unroll
    for (int kk = 0; kk < 2; ++kk) {
      const int cb = kk * 64 + ks * 16;
      bf8v av[4], bv[8];
#pragma unroll
      for (int m = 0; m < 4; ++m) av[m] = ldfrag(Ps, w * 64 + m * 16 + fr, cb);
#pragma unroll
      for (int n = 0; n < 8; ++n) bv[n] = ldfrag(Xs, n * 16 + fr, cb);
#pragma unroll
      for (int m = 0; m < 4; ++m)
#pragma unroll
        for (int n = 0; n < 8; ++n) acc[m][n] = MFMA16(av[m], bv[n], acc[m][n]);
    }
    // relu -> Kt (LDS, [m][l]) + kp (global, [l][m], packed 8B)
#pragma unroll
    for (int m = 0; m < 4; ++m)
#pragma unroll
      for (int n = 0; n < 8; ++n) {
        const int mb = w * 64 + m * 16 + fq * 4;
        const int ll = n * 16 + fr;
        ushort_t bvv[4];
#pragma unroll
        for (int j = 0; j < 4; ++j) {
          float v = fmaxf(RATIO * acc[m][n][j], 0.f) + STABC;
          bvv[j] = f2bf(v);
          *(ushort_t*)((char*)Kt + (mb + j) * 256 + ((ll * 2) ^ (((mb + j) & 7) << 4))) = bvv[j];
        }
        uint2 pk;
        pk.x = (uint32_t)bvv[0] | ((uint32_t)bvv[1] << 16);
        pk.y = (uint32_t)bvv[2] | ((uint32_t)bvv[3] << 16);
        *(uint2*)(kp + ((size_t)bh * L_ + l0 + ll) * M_ + mb) = pk;
      }
  }
  __syncthreads();
  // S partials: A = [VT;ones] (rows d 0..64), B = Kt rows m, K = 128 tokens
  f4v accS[5][4] = {};
  for (int kt = 0; kt < 2; ++kt) {
#pragma unroll
    for (int i = 0; i < 2; ++i)
      gll16(VT + ((size_t)bh * 64 + i * 32 + srow) * L_ + l0 + kt * 64 + scol, (char*)Xs + i * 4096 + w * 1024);
    if (tid < 32) ((uint32_t*)Xs)[2048 + tid] = 0x3f803f80u;   // ones row 64
    __syncthreads();
#pragma unroll
    for (int kk = 0; kk < 2; ++kk) {
      const int cbA = kk * 64 + ks * 16;
      const int cbK = kt * 128 + kk * 64 + ks * 16;
      bf8v av[5], bv[4];
#pragma unroll
      for (int a = 0; a < 5; ++a) av[a] = ldfrag(Xs, a * 16 + fr, cbA);
#pragma unroll
      for (int n = 0; n < 4; ++n) bv[n] = ldfrag256(Kt, w * 64 + n * 16 + fr, cbK);
#pragma unroll
      for (int a = 0; a < 5; ++a)
#pragma unroll
        for (int n = 0; n < 4; ++n) accS[a][n] = MFMA16(av[a], bv[n], accS[a][n]);
    }
    __syncthreads();
  }
  const size_t base = ((size_t)bh * NC + ci) * 65;
#pragma unroll
  for (int a = 0; a < 5; ++a)
#pragma unroll
    for (int n = 0; n < 4; ++n)
#pragma unroll
      for (int j = 0; j < 4; ++j) {
        int row = a * 16 + fq * 4 + j;
        if (row < 65) S[(base + row) * M_ + w * 64 + n * 16 + fr] = f2bf(accS[a][n][j]);
      }
}

// ---------------- exclusive prefix over chunks, vectorized, parallel loads ----------------
__global__ __launch_bounds__(256) void prefix2_k(ushort_t* __restrict__ S) {
  const int g = blockIdx.x * 256 + threadIdx.x;   // 66560 = 32 bh * 2080 uint4-cols
  const int bh = g / 2080, r = g - bh * 2080;
  ushort_t* base = S + (size_t)bh * (NC * 65 * M_) + (size_t)r * 8;
  uint4 v[16];
#pragma unroll
  for (int ci = 0; ci < NC; ++ci) v[ci] = *(const uint4*)(base + (size_t)ci * (65 * M_));
  float c[8] = {};
#pragma unroll
  for (int ci = 0; ci < NC; ++ci) {
    union { uint4 u; ushort_t s[8]; } in, out;
    in.u = v[ci];
#pragma unroll
    for (int e = 0; e < 8; ++e) {
      float t = bf2f(in.s[e]);
      out.s[e] = f2bf(c[e]);
      c[e] += t;
    }
    *(uint4*)(base + (size_t)ci * (65 * M_)) = out.u;
  }
}

// ---------------- qkout2: A = mask(qp@kp^T); out = [A|qp]@[[VT;1];[S;sk]]; qp staged once ----------------
__global__ __launch_bounds__(256) void qkout2_k(const ushort_t* __restrict__ qp, const ushort_t* __restrict__ kp,
                                                const ushort_t* __restrict__ VT, const ushort_t* __restrict__ S,
                                                ushort_t* __restrict__ attn) {
  __shared__ ushort_t As[128 * 64];   // qp slice (16 KB)
  __shared__ ushort_t Bs[128 * 64];   // kp slice (16 KB)
  __shared__ ushort_t Ss[80 * 64];    // S rows / VT rows + ones (10 KB)
  __shared__ ushort_t At[128 * 128];  // masked A, 256B rows swizzled (32 KB)
  const int ci = blockIdx.x, bh = blockIdx.y;
  const int tid = threadIdx.x, lane = tid & 63, w = tid >> 6;
  const int srow = w * 8 + (lane >> 3);
  const int scol = (((lane & 7) * 16) ^ ((lane >> 3) << 4)) >> 1;
  const int fr = lane & 15, ks = lane >> 4, fq = lane >> 4;
  const int wr = (w >> 1) * 64, wc = (w & 1) * 64;
  const size_t rowb = (size_t)bh * L_ + ci * CHK;
  const size_t sbase = ((size_t)bh * NC + ci) * 65;
  f4v acc[4][4] = {};    // QK^T (64x64 per wave)
  f4v acc2[2][5] = {};   // output (32 rows x 80 cols per wave)
  for (int kt = 0; kt < 4; ++kt) {
#pragma unroll
    for (int i = 0; i < 4; ++i) {
      int r = i * 32 + srow;
      gll16(qp + (rowb + r) * M_ + kt * 64 + scol, (char*)As + i * 4096 + w * 1024);
      gll16(kp + (rowb + r) * M_ + kt * 64 + scol, (char*)Bs + i * 4096 + w * 1024);
    }
#pragma unroll
    for (int i = 0; i < 2; ++i)
      gll16(S + (sbase + i * 32 + srow) * M_ + kt * 64 + scol, (char*)Ss + i * 4096 + w * 1024);
    if (tid < 32)
      ((uint32_t*)Ss)[2048 + tid] = ((const uint32_t*)(S + (sbase + 64) * M_ + kt * 64))[tid];   // sk row
    __syncthreads();
#pragma unroll
    for (int kk = 0; kk < 2; ++kk) {
      const int cb = kk * 64 + ks * 16;
      bf8v av[4], bv[4], a2[2], sv[5];
#pragma unroll
      for (int m = 0; m < 4; ++m) av[m] = ldfrag(As, wr + m * 16 + fr, cb);
#pragma unroll
      for (int n = 0; n < 4; ++n) bv[n] = ldfrag(Bs, wc + n * 16 + fr, cb);
#pragma unroll
      for (int m = 0; m < 4; ++m)
#pragma unroll
        for (int n = 0; n < 4; ++n) acc[m][n] = MFMA16(av[m], bv[n], acc[m][n]);
#pragma unroll
      for (int m = 0; m < 2; ++m) a2[m] = ldfrag(As, w * 32 + m * 16 + fr, cb);
#pragma unroll
      for (int n = 0; n < 5; ++n) sv[n] = ldfrag(Ss, n * 16 + fr, cb);
#pragma unroll
      for (int m = 0; m < 2; ++m)
#pragma unroll
        for (int n = 0; n < 5; ++n) acc2[m][n] = MFMA16(a2[m], sv[n], acc2[m][n]);
    }
    __syncthreads();
  }
  // masked A -> At
#pragma unroll
  for (int m = 0; m < 4; ++m)
#pragma unroll
    for (int n = 0; n < 4; ++n)
#pragma unroll
      for (int j = 0; j < 4; ++j) {
        int row = wr + m * 16 + fq * 4 + j;
        int col = wc + n * 16 + fr;
        float v = (col <= row) ? acc[m][n][j] : 0.f;
        *(ushort_t*)((char*)At + row * 256 + ((col * 2) ^ ((row & 7) << 4))) = f2bf(v);
      }
  __syncthreads();
  // intra-chunk: A @ [VT;ones]
  for (int kt2 = 0; kt2 < 2; ++kt2) {
#pragma unroll
    for (int i = 0; i < 2; ++i)
      gll16(VT + ((size_t)bh * 64 + i * 32 + srow) * L_ + ci * CHK + kt2 * 64 + scol,
            (char*)Ss + i * 4096 + w * 1024);
    if (tid < 32) ((uint32_t*)Ss)[2048 + tid] = 0x3f803f80u;   // ones row
    __syncthreads();
#pragma unroll
    for (int kk = 0; kk < 2; ++kk) {
      const int cb = kk * 64 + ks * 16;
      bf8v a2[2], sv[5];
#pragma unroll
      for (int m = 0; m < 2; ++m) a2[m] = ldfrag256(At, w * 32 + m * 16 + fr, kt2 * 128 + cb);
#pragma unroll
      for (int n = 0; n < 5; ++n) sv[n] = ldfrag(Ss, n * 16 + fr, cb);
#pragma unroll
      for (int m = 0; m < 2; ++m)
#pragma unroll
        for (int n = 0; n < 5; ++n) acc2[m][n] = MFMA16(a2[m], sv[n], acc2[m][n]);
    }
    __syncthreads();
  }
  const int b = bh >> 3, h = bh & 7;
#pragma unroll
  for (int m = 0; m < 2; ++m) {
    float dinv[4];
#pragma unroll
    for (int j = 0; j < 4; ++j) {
      float den = __shfl(acc2[m][4][j], (lane & 48));   // col 64 lives at fr==0
      dinv[j] = 1.f / den;
    }
#pragma unroll
    for (int n = 0; n < 4; ++n)
#pragma unroll
      for (int j = 0; j < 4; ++j) {
        int l = ci * CHK + w * 32 + m * 16 + fq * 4 + j;
        int col = h * 64 + n * 16 + fr;
        attn[((size_t)(b * L_ + l)) * DIM_ + col] = f2bf(acc2[m][n][j] * dinv[j]);
      }
  }
}

extern "C" void kernel_launch(void* const* d_in, const int* in_sizes, int n_in,
                              void* d_out, int out_size, void* d_ws, size_t ws_size,
                              hipStream_t stream) {
  const float* query = (const float*)d_in[0];
  const float* key   = (const float*)d_in[1];
  const float* value = (const float*)d_in[2];
  const float* proj  = (const float*)d_in[3];
  const float* wq = (const float*)d_in[4];
  const float* bq = (const float*)d_in[5];
  const float* wk = (const float*)d_in[6];
  const float* bk = (const float*)d_in[7];
  const float* wv = (const float*)d_in[8];
  const float* bv = (const float*)d_in[9];
  const float* wo = (const float*)d_in[10];
  const float* bo = (const float*)d_in[11];

  char* ws = (char*)d_ws;
  ushort_t* Wc   = (ushort_t*)(ws);                 // weights+proj bf16: 2,129,920 B
  ushort_t* Xq   = (ushort_t*)(ws + 2129920);       // 8 MB
  ushort_t* Xk   = (ushort_t*)(ws + 10518528);      // 8 MB
  ushort_t* Xv   = (ushort_t*)(ws + 18907136);      // 8 MB
  ushort_t* XHq  = (ushort_t*)(ws + 27295744);      // 8 MB
  ushort_t* XHk  = (ushort_t*)(ws + 35684352);      // 8 MB
  ushort_t* VT   = (ushort_t*)(ws + 44072960);      // 8 MB [bh][64][2048]
  ushort_t* qp   = (ushort_t*)(ws + 52461568);      // 32 MB [bh][2048][256]
  ushort_t* kp   = (ushort_t*)(ws + 86016000);      // 32 MB [bh][2048][256]
  ushort_t* Skv  = (ushort_t*)(ws + 119570432);     // 17.04 MB [bh][16][65][256]
  ushort_t* attb = (ushort_t*)Xq;                   // Xq dead after gemmQ -> reuse for attn
  const ushort_t* Wq = Wc;
  const ushort_t* Wk = Wc + 262144;
  const ushort_t* Wv = Wc + 524288;
  const ushort_t* Wo = Wc + 786432;
  const ushort_t* Pc = Wc + 1048576;

  dim3 blk(256);
  cvt_all<<<6664, blk, 0, stream>>>(query, key, value, wq, wk, wv, wo, proj, Xq, Xk, Xv, Wc);
  gemm512b<2><<<dim3(64, 8), blk, 0, stream>>>(Xv, Wv, bv, nullptr, VT);
  gemm512b<1><<<dim3(64, 8), blk, 0, stream>>>(Xq, Wq, bq, XHq, nullptr);
  feat_k<<<dim3(64, 2, 8), blk, 0, stream>>>(XHq, Pc, qp);
  gemm512b<1><<<dim3(64, 8), blk, 0, stream>>>(Xk, Wk, bk, XHk, nullptr);
  cp2_k<<<dim3(NC, BH), blk, 0, stream>>>(XHk, Pc, VT, kp, Skv);
  prefix2_k<<<260, blk, 0, stream>>>(Skv);
  qkout2_k<<<dim3(NC, BH), blk, 0, stream>>>(qp, kp, VT, Skv, attb);
  gemm512b<0><<<dim3(64, 8), blk, 0, stream>>>(attb, Wo, bo, (float*)d_out, nullptr);
}

// Round 6
// 103.710 us; speedup vs baseline: 6.2202x; 1.1576x over previous
//
#include <hip/hip_runtime.h>
#include <stdint.h>

#define B_ 4
#define L_ 2048
#define H_ 8
#define DK 64
#define M_ 256
#define DIM_ 512
#define NTOK (B_ * L_)
#define CHK 128
#define NC (L_ / CHK)
#define BH (B_ * H_)
#define RATIO 0.0625f
#define STABC 1e-5f

typedef unsigned short ushort_t;
typedef __attribute__((ext_vector_type(8))) short bf8v;   // 8 bf16 = 4 VGPR
typedef __attribute__((ext_vector_type(4))) float f4v;    // MFMA accumulator

#define MFMA16(a, b, c) __builtin_amdgcn_mfma_f32_16x16x32_bf16(a, b, c, 0, 0, 0)

__device__ __forceinline__ ushort_t f2bf(float f) {
  uint32_t u = __float_as_uint(f);
  return (ushort_t)((u + 0x7fffu + ((u >> 16) & 1u)) >> 16);
}
__device__ __forceinline__ float bf2f(ushort_t u) { return __uint_as_float(((uint32_t)u) << 16); }

__device__ __forceinline__ void gll16(const void* g, void* l) {
  __builtin_amdgcn_global_load_lds((const __attribute__((address_space(1))) void*)g,
                                   (__attribute__((address_space(3))) void*)l, 16, 0, 0);
}

// XOR-swizzled LDS tiles; row strides 128/256/512 B
__device__ __forceinline__ bf8v ldfrag(const ushort_t* base, int row, int cb) {
  return *(const bf8v*)((const char*)base + row * 128 + (cb ^ ((row & 7) << 4)));
}
__device__ __forceinline__ bf8v ldfrag256(const ushort_t* base, int row, int cb) {
  return *(const bf8v*)((const char*)base + row * 256 + (cb ^ ((row & 7) << 4)));
}
__device__ __forceinline__ bf8v ldfrag512(const ushort_t* base, int row, int cb) {
  return *(const bf8v*)((const char*)base + row * 512 + (cb ^ ((row & 7) << 4)));
}

// ---------------- bf16 convert of weights + proj only ----------------
__global__ __launch_bounds__(256) void cvt_w(const float* __restrict__ wq, const float* __restrict__ wk,
                                             const float* __restrict__ wv, const float* __restrict__ wo,
                                             const float* __restrict__ pj, ushort_t* __restrict__ d) {
  int i = (blockIdx.x * 256 + threadIdx.x) * 8;   // 520 blocks covers 1,064,960 elems exactly
  const float* s;
  int off;
  if (i < 262144)       { s = wq; off = i; }
  else if (i < 524288)  { s = wk; off = i - 262144; }
  else if (i < 786432)  { s = wv; off = i - 524288; }
  else if (i < 1048576) { s = wo; off = i - 786432; }
  else                  { s = pj; off = i - 1048576; }
  float4 a = *(const float4*)(s + off);
  float4 b = *(const float4*)(s + off + 4);
  union { ushort_t u[8]; uint4 vv; } o;
  o.u[0] = f2bf(a.x); o.u[1] = f2bf(a.y); o.u[2] = f2bf(a.z); o.u[3] = f2bf(a.w);
  o.u[4] = f2bf(b.x); o.u[5] = f2bf(b.y); o.u[6] = f2bf(b.z); o.u[7] = f2bf(b.w);
  *(uint4*)(d + i) = o.vv;
}

// ---------------- fused Q/K/V projection GEMM, fp32 input reg-staged to bf16 LDS ----------------
// grid (64, 8, 3): z=0 query->XHq, z=1 key->XHk, z=2 value->VT (transposed head-slices)
__global__ __launch_bounds__(256) void qkvgemm_k(const float* __restrict__ q, const float* __restrict__ k,
                                                 const float* __restrict__ v, const ushort_t* __restrict__ Wc,
                                                 const float* __restrict__ bq, const float* __restrict__ bk,
                                                 const float* __restrict__ bv, ushort_t* __restrict__ XHq,
                                                 ushort_t* __restrict__ XHk, ushort_t* __restrict__ VT) {
  __shared__ ushort_t As[128 * 64];
  __shared__ ushort_t Bs[64 * 64];
  const int z = blockIdx.z;
  const float* X = (z == 0) ? q : (z == 1) ? k : v;
  const ushort_t* Bw = Wc + (size_t)z * 262144;
  const float* bias = (z == 0) ? bq : (z == 1) ? bk : bv;
  const int tid = threadIdx.x, lane = tid & 63, w = tid >> 6;
  const int bm = blockIdx.x * 128, bn = blockIdx.y * 64;
  const int srow = w * 8 + (lane >> 3);
  const int scol = (((lane & 7) * 16) ^ ((lane >> 3) << 4)) >> 1;
  const int wr = (w >> 1) * 64, wc = (w & 1) * 32;
  const int fr = lane & 15, ks = lane >> 4, fq = lane >> 4;
  f4v acc[4][2] = {};
  for (int k0 = 0; k0 < DIM_; k0 += 64) {
    // B (weights, bf16) async
#pragma unroll
    for (int i = 0; i < 2; ++i)
      gll16(Bw + (size_t)(bn + i * 32 + srow) * DIM_ + k0 + scol, (char*)Bs + i * 4096 + w * 1024);
    // A (fp32 -> bf16, swizzled ds_write)
#pragma unroll
    for (int i = 0; i < 4; ++i) {
      int e = tid + i * 256;
      int r = e >> 3, g = e & 7;
      const float* src = X + (size_t)(bm + r) * DIM_ + k0 + g * 8;
      float4 f0 = *(const float4*)src;
      float4 f1 = *(const float4*)(src + 4);
      union { ushort_t u[8]; bf8v v8; } pk;
      pk.u[0] = f2bf(f0.x); pk.u[1] = f2bf(f0.y); pk.u[2] = f2bf(f0.z); pk.u[3] = f2bf(f0.w);
      pk.u[4] = f2bf(f1.x); pk.u[5] = f2bf(f1.y); pk.u[6] = f2bf(f1.z); pk.u[7] = f2bf(f1.w);
      *(bf8v*)((char*)As + r * 128 + ((g * 16) ^ ((r & 7) << 4))) = pk.v8;
    }
    __syncthreads();
#pragma unroll
    for (int kk = 0; kk < 2; ++kk) {
      const int cb = kk * 64 + ks * 16;
      bf8v av[4], bv2[2];
#pragma unroll
      for (int m = 0; m < 4; ++m) av[m] = ldfrag(As, wr + m * 16 + fr, cb);
#pragma unroll
      for (int n = 0; n < 2; ++n) bv2[n] = ldfrag(Bs, wc + n * 16 + fr, cb);
#pragma unroll
      for (int m = 0; m < 4; ++m)
#pragma unroll
        for (int n = 0; n < 2; ++n) acc[m][n] = MFMA16(av[m], bv2[n], acc[m][n]);
    }
    __syncthreads();
  }
  if (z == 2) {   // V path: transpose head slice -> VT[bh][64][2048]
    __shared__ ushort_t Tt[64 * 136];
#pragma unroll
    for (int m = 0; m < 4; ++m)
#pragma unroll
      for (int n = 0; n < 2; ++n) {
        int cl = wc + n * 16 + fr;
        float bsv = bias[bn + cl];
#pragma unroll
        for (int j = 0; j < 4; ++j) {
          int rl = wr + m * 16 + fq * 4 + j;
          Tt[cl * 136 + rl] = f2bf(acc[m][n][j] + bsv);
        }
      }
    __syncthreads();
    const int d = tid >> 2, seg = tid & 3;
    const int b = bm >> 11, h = blockIdx.y, l0 = bm & 2047;
    size_t vbase = ((size_t)((b * 8 + h) * 64 + d)) * L_ + l0 + seg * 32;
#pragma unroll
    for (int qq = 0; qq < 4; ++qq)
      *(uint4*)&VT[vbase + qq * 8] = *(const uint4*)&Tt[d * 136 + seg * 32 + qq * 8];
  } else {
    ushort_t* Y = (z == 0) ? XHq : XHk;
#pragma unroll
    for (int m = 0; m < 4; ++m)
#pragma unroll
      for (int n = 0; n < 2; ++n) {
        int col = bn + wc + n * 16 + fr;
        float bsv = bias[col];
#pragma unroll
        for (int j = 0; j < 4; ++j) {
          int row = bm + wr + m * 16 + fq * 4 + j;
          Y[(size_t)row * DIM_ + col] = f2bf(acc[m][n][j] + bsv);
        }
      }
  }
}

// ---------------- cp2: fused kp-feature + per-chunk partials ----------------
__global__ __launch_bounds__(256) void cp2_k(const ushort_t* __restrict__ XHk, const ushort_t* __restrict__ P,
                                             const ushort_t* __restrict__ VT, ushort_t* __restrict__ kp,
                                             ushort_t* __restrict__ S) {
  __shared__ ushort_t Ps[256 * 64];    // proj (32 KB)
  __shared__ ushort_t Xs[128 * 64];    // XHk chunk, then [VT;ones] (16 KB)
  __shared__ ushort_t Kt[256 * 128];   // kpT [m][l], 256B rows swizzled (64 KB)
  const int ci = blockIdx.x, bh = blockIdx.y;
  const int b = bh >> 3, h = bh & 7;
  const int tid = threadIdx.x, lane = tid & 63, w = tid >> 6;
  const int srow = w * 8 + (lane >> 3);
  const int scol = (((lane & 7) * 16) ^ ((lane >> 3) << 4)) >> 1;
  const int fr = lane & 15, ks = lane >> 4, fq = lane >> 4;
  const int l0 = ci * CHK;
#pragma unroll
  for (int i = 0; i < 8; ++i)
    gll16(P + (size_t)(i * 32 + srow) * 64 + scol, (char*)Ps + i * 4096 + w * 1024);
#pragma unroll
  for (int i = 0; i < 4; ++i)
    gll16(XHk + (size_t)(b * L_ + l0 + i * 32 + srow) * DIM_ + h * 64 + scol, (char*)Xs + i * 4096 + w * 1024);
  __syncthreads();
  {
    f4v acc[4][8] = {};
#pragma unroll
    for (int kk = 0; kk < 2; ++kk) {
      const int cb = kk * 64 + ks * 16;
      bf8v av[4], bv[8];
#pragma unroll
      for (int m = 0; m < 4; ++m) av[m] = ldfrag(Ps, w * 64 + m * 16 + fr, cb);
#pragma unroll
      for (int n = 0; n < 8; ++n) bv[n] = ldfrag(Xs, n * 16 + fr, cb);
#pragma unroll
      for (int m = 0; m < 4; ++m)
#pragma unroll
        for (int n = 0; n < 8; ++n) acc[m][n] = MFMA16(av[m], bv[n], acc[m][n]);
    }
#pragma unroll
    for (int m = 0; m < 4; ++m)
#pragma unroll
      for (int n = 0; n < 8; ++n) {
        const int mb = w * 64 + m * 16 + fq * 4;
        const int ll = n * 16 + fr;
        ushort_t bvv[4];
#pragma unroll
        for (int j = 0; j < 4; ++j) {
          float v = fmaxf(RATIO * acc[m][n][j], 0.f) + STABC;
          bvv[j] = f2bf(v);
          *(ushort_t*)((char*)Kt + (mb + j) * 256 + ((ll * 2) ^ (((mb + j) & 7) << 4))) = bvv[j];
        }
        uint2 pk;
        pk.x = (uint32_t)bvv[0] | ((uint32_t)bvv[1] << 16);
        pk.y = (uint32_t)bvv[2] | ((uint32_t)bvv[3] << 16);
        *(uint2*)(kp + ((size_t)bh * L_ + l0 + ll) * M_ + mb) = pk;
      }
  }
  __syncthreads();
  f4v accS[5][4] = {};
  for (int kt = 0; kt < 2; ++kt) {
#pragma unroll
    for (int i = 0; i < 2; ++i)
      gll16(VT + ((size_t)bh * 64 + i * 32 + srow) * L_ + l0 + kt * 64 + scol, (char*)Xs + i * 4096 + w * 1024);
    if (tid < 32) ((uint32_t*)Xs)[2048 + tid] = 0x3f803f80u;
    __syncthreads();
#pragma unroll
    for (int kk = 0; kk < 2; ++kk) {
      const int cbA = kk * 64 + ks * 16;
      const int cbK = kt * 128 + kk * 64 + ks * 16;
      bf8v av[5], bv[4];
#pragma unroll
      for (int a = 0; a < 5; ++a) av[a] = ldfrag(Xs, a * 16 + fr, cbA);
#pragma unroll
      for (int n = 0; n < 4; ++n) bv[n] = ldfrag256(Kt, w * 64 + n * 16 + fr, cbK);
#pragma unroll
      for (int a = 0; a < 5; ++a)
#pragma unroll
        for (int n = 0; n < 4; ++n) accS[a][n] = MFMA16(av[a], bv[n], accS[a][n]);
    }
    __syncthreads();
  }
  const size_t base = ((size_t)bh * NC + ci) * 65;
#pragma unroll
  for (int a = 0; a < 5; ++a)
#pragma unroll
    for (int n = 0; n < 4; ++n)
#pragma unroll
      for (int j = 0; j < 4; ++j) {
        int row = a * 16 + fq * 4 + j;
        if (row < 65) S[(base + row) * M_ + w * 64 + n * 16 + fr] = f2bf(accS[a][n][j]);
      }
}

// ---------------- exclusive prefix over chunks ----------------
__global__ __launch_bounds__(256) void prefix2_k(ushort_t* __restrict__ S) {
  const int g = blockIdx.x * 256 + threadIdx.x;
  const int bh = g / 2080, r = g - bh * 2080;
  ushort_t* base = S + (size_t)bh * (NC * 65 * M_) + (size_t)r * 8;
  uint4 v[16];
#pragma unroll
  for (int ci = 0; ci < NC; ++ci) v[ci] = *(const uint4*)(base + (size_t)ci * (65 * M_));
  float c[8] = {};
#pragma unroll
  for (int ci = 0; ci < NC; ++ci) {
    union { uint4 u; ushort_t s[8]; } in, out;
    in.u = v[ci];
#pragma unroll
    for (int e = 0; e < 8; ++e) {
      float t = bf2f(in.s[e]);
      out.s[e] = f2bf(c[e]);
      c[e] += t;
    }
    *(uint4*)(base + (size_t)ci * (65 * M_)) = out.u;
  }
}

// ---------------- qkout3: in-LDS qp-feature + QK^T + qp@S + A@[VT;1] ----------------
// 512 threads (8 waves), grid (NC, BH). LDS 112 KB:
//   Qp [128 tok][256 feat] swz512 : 0 .. 65536
//   R1 (32 KB): Ps / Ks / At      : 65536 .. 98304
//   R2 (16 KB): Xs / Ss           : 98304 .. 114688
__global__ __launch_bounds__(512) void qkout3_k(const ushort_t* __restrict__ XHq, const ushort_t* __restrict__ P,
                                                const ushort_t* __restrict__ kp, const ushort_t* __restrict__ VT,
                                                const ushort_t* __restrict__ S, ushort_t* __restrict__ attn) {
  __shared__ char LB[114688];
  ushort_t* Qp = (ushort_t*)LB;
  ushort_t* R1 = (ushort_t*)(LB + 65536);
  ushort_t* R2 = (ushort_t*)(LB + 98304);
  const int ci = blockIdx.x, bh = blockIdx.y;
  const int b = bh >> 3, h = bh & 7;
  const int tid = threadIdx.x, lane = tid & 63, w = tid >> 6;   // w 0..7
  const int srow = w * 8 + (lane >> 3);
  const int scol = (((lane & 7) * 16) ^ ((lane >> 3) << 4)) >> 1;
  const int fr = lane & 15, ks = lane >> 4, fq = lane >> 4;
  const int l0 = ci * CHK;
  const size_t rowb = (size_t)bh * L_ + l0;            // [bh][L] index: kp only!
  const size_t tokb = (size_t)b * L_ + l0;             // [token] index: XHq / attn
  const size_t sbase = ((size_t)bh * NC + ci) * 65;
  // ---- phase 0: stage proj + XHq chunk; compute qp -> Qp ----
#pragma unroll
  for (int i = 0; i < 4; ++i)
    gll16(P + (size_t)(i * 64 + srow) * 64 + scol, (char*)R1 + i * 8192 + w * 1024);
#pragma unroll
  for (int i = 0; i < 2; ++i)
    gll16(XHq + (tokb + i * 64 + srow) * DIM_ + h * 64 + scol, (char*)R2 + i * 8192 + w * 1024);   // FIX: tokb not rowb
  __syncthreads();
  {
    f4v accF[2][8] = {};
#pragma unroll
    for (int kk = 0; kk < 2; ++kk) {
      const int cb = kk * 64 + ks * 16;
      bf8v av[2], bv[8];
#pragma unroll
      for (int m = 0; m < 2; ++m) av[m] = ldfrag(R1, w * 32 + m * 16 + fr, cb);
#pragma unroll
      for (int n = 0; n < 8; ++n) bv[n] = ldfrag(R2, n * 16 + fr, cb);
#pragma unroll
      for (int m = 0; m < 2; ++m)
#pragma unroll
        for (int n = 0; n < 8; ++n) accF[m][n] = MFMA16(av[m], bv[n], accF[m][n]);
    }
#pragma unroll
    for (int m = 0; m < 2; ++m)
#pragma unroll
      for (int n = 0; n < 8; ++n) {
        const int mb = w * 32 + m * 16 + fq * 4;   // feature index (4 consecutive)
        const int ll = n * 16 + fr;                // token row
        ushort_t bvv[4];
#pragma unroll
        for (int j = 0; j < 4; ++j)
          bvv[j] = f2bf(fmaxf(RATIO * accF[m][n][j], 0.f) + STABC);
        uint2 pk;
        pk.x = (uint32_t)bvv[0] | ((uint32_t)bvv[1] << 16);
        pk.y = (uint32_t)bvv[2] | ((uint32_t)bvv[3] << 16);
        *(uint2*)((char*)Qp + ll * 512 + ((mb * 2) ^ ((ll & 7) << 4))) = pk;
      }
  }
  __syncthreads();
  // ---- phase 1: QK^T (accA) + qp@[S;sk] (acc2), kt over 4 x 64 features ----
  const int qr = (w & 3) * 32, qc = (w >> 2) * 64;
  const int orow = w * 16;
  f4v accA[2][4] = {};
  f4v acc2[5] = {};
  for (int kt = 0; kt < 4; ++kt) {
#pragma unroll
    for (int i = 0; i < 2; ++i)
      gll16(kp + (rowb + i * 64 + srow) * M_ + kt * 64 + scol, (char*)R1 + i * 8192 + w * 1024);
    gll16(S + (sbase + srow) * M_ + kt * 64 + scol, (char*)R2 + w * 1024);
    if (tid < 32)
      ((uint32_t*)R2)[2048 + tid] = ((const uint32_t*)(S + (sbase + 64) * M_ + kt * 64))[tid];
    __syncthreads();
#pragma unroll
    for (int kk = 0; kk < 2; ++kk) {
      const int cb = kk * 64 + ks * 16;
      const int cbQ = kt * 128 + cb;
      bf8v aq[2], bk_[4], a2, sv[5];
#pragma unroll
      for (int m = 0; m < 2; ++m) aq[m] = ldfrag512(Qp, qr + m * 16 + fr, cbQ);
#pragma unroll
      for (int n = 0; n < 4; ++n) bk_[n] = ldfrag(R1, qc + n * 16 + fr, cb);
#pragma unroll
      for (int m = 0; m < 2; ++m)
#pragma unroll
        for (int n = 0; n < 4; ++n) accA[m][n] = MFMA16(aq[m], bk_[n], accA[m][n]);
      a2 = ldfrag512(Qp, orow + fr, cbQ);
#pragma unroll
      for (int n = 0; n < 5; ++n) sv[n] = ldfrag(R2, n * 16 + fr, cb);
#pragma unroll
      for (int n = 0; n < 5; ++n) acc2[n] = MFMA16(a2, sv[n], acc2[n]);
    }
    __syncthreads();
  }
  // ---- phase 2: masked A -> At ----
#pragma unroll
  for (int m = 0; m < 2; ++m)
#pragma unroll
    for (int n = 0; n < 4; ++n)
#pragma unroll
      for (int j = 0; j < 4; ++j) {
        int row = qr + m * 16 + fq * 4 + j;
        int col = qc + n * 16 + fr;
        float v = (col <= row) ? accA[m][n][j] : 0.f;
        *(ushort_t*)((char*)R1 + row * 256 + ((col * 2) ^ ((row & 7) << 4))) = f2bf(v);
      }
  __syncthreads();
  // ---- phase 3: A @ [VT; ones] ----
  for (int kt2 = 0; kt2 < 2; ++kt2) {
    gll16(VT + ((size_t)bh * 64 + srow) * L_ + l0 + kt2 * 64 + scol, (char*)R2 + w * 1024);
    if (tid < 32) ((uint32_t*)R2)[2048 + tid] = 0x3f803f80u;
    __syncthreads();
#pragma unroll
    for (int kk = 0; kk < 2; ++kk) {
      const int cb = kk * 64 + ks * 16;
      bf8v a3, sv[5];
      a3 = ldfrag256(R1, orow + fr, kt2 * 128 + cb);
#pragma unroll
      for (int n = 0; n < 5; ++n) sv[n] = ldfrag(R2, n * 16 + fr, cb);
#pragma unroll
      for (int n = 0; n < 5; ++n) acc2[n] = MFMA16(a3, sv[n], acc2[n]);
    }
    __syncthreads();
  }
  // ---- epilogue ----
  float dinv[4];
#pragma unroll
  for (int j = 0; j < 4; ++j) {
    float den = __shfl(acc2[4][j], (lane & 48));   // col 64 lives at fr==0
    dinv[j] = 1.f / den;
  }
#pragma unroll
  for (int n = 0; n < 4; ++n)
#pragma unroll
    for (int j = 0; j < 4; ++j) {
      int l = orow + fq * 4 + j;
      int col = h * 64 + n * 16 + fr;
      attn[(tokb + l) * DIM_ + col] = f2bf(acc2[n][j] * dinv[j]);
    }
}

// ---------------- output projection: fp32 out = attb @ Wo^T + bo ----------------
__global__ __launch_bounds__(256) void gemmo_k(const ushort_t* __restrict__ A, const ushort_t* __restrict__ Bw,
                                               const float* __restrict__ bias, float* __restrict__ Y) {
  __shared__ ushort_t As[128 * 64];
  __shared__ ushort_t Bs[64 * 64];
  const int tid = threadIdx.x, lane = tid & 63, w = tid >> 6;
  const int bm = blockIdx.x * 128, bn = blockIdx.y * 64;
  const int srow = w * 8 + (lane >> 3);
  const int scol = (((lane & 7) * 16) ^ ((lane >> 3) << 4)) >> 1;
  const int wr = (w >> 1) * 64, wc = (w & 1) * 32;
  const int fr = lane & 15, ks = lane >> 4, fq = lane >> 4;
  f4v acc[4][2] = {};
  for (int k0 = 0; k0 < DIM_; k0 += 64) {
#pragma unroll
    for (int i = 0; i < 4; ++i)
      gll16(A + (size_t)(bm + i * 32 + srow) * DIM_ + k0 + scol, (char*)As + i * 4096 + w * 1024);
#pragma unroll
    for (int i = 0; i < 2; ++i)
      gll16(Bw + (size_t)(bn + i * 32 + srow) * DIM_ + k0 + scol, (char*)Bs + i * 4096 + w * 1024);
    __syncthreads();
#pragma unroll
    for (int kk = 0; kk < 2; ++kk) {
      const int cb = kk * 64 + ks * 16;
      bf8v av[4], bv[2];
#pragma unroll
      for (int m = 0; m < 4; ++m) av[m] = ldfrag(As, wr + m * 16 + fr, cb);
#pragma unroll
      for (int n = 0; n < 2; ++n) bv[n] = ldfrag(Bs, wc + n * 16 + fr, cb);
#pragma unroll
      for (int m = 0; m < 4; ++m)
#pragma unroll
        for (int n = 0; n < 2; ++n) acc[m][n] = MFMA16(av[m], bv[n], acc[m][n]);
    }
    __syncthreads();
  }
#pragma unroll
  for (int m = 0; m < 4; ++m)
#pragma unroll
    for (int n = 0; n < 2; ++n) {
      int col = bn + wc + n * 16 + fr;
      float bsv = bias[col];
#pragma unroll
      for (int j = 0; j < 4; ++j) {
        int row = bm + wr + m * 16 + fq * 4 + j;
        Y[(size_t)row * DIM_ + col] = acc[m][n][j] + bsv;
      }
    }
}

extern "C" void kernel_launch(void* const* d_in, const int* in_sizes, int n_in,
                              void* d_out, int out_size, void* d_ws, size_t ws_size,
                              hipStream_t stream) {
  const float* query = (const float*)d_in[0];
  const float* key   = (const float*)d_in[1];
  const float* value = (const float*)d_in[2];
  const float* proj  = (const float*)d_in[3];
  const float* wq = (const float*)d_in[4];
  const float* bq = (const float*)d_in[5];
  const float* wk = (const float*)d_in[6];
  const float* bk = (const float*)d_in[7];
  const float* wv = (const float*)d_in[8];
  const float* bv = (const float*)d_in[9];
  const float* wo = (const float*)d_in[10];
  const float* bo = (const float*)d_in[11];

  char* ws = (char*)d_ws;
  ushort_t* Wc   = (ushort_t*)(ws);                 // weights+proj bf16: 2,129,920 B
  ushort_t* XHq  = (ushort_t*)(ws + 2129920);       // 8 MB
  ushort_t* XHk  = (ushort_t*)(ws + 10518528);      // 8 MB
  ushort_t* VT   = (ushort_t*)(ws + 18907136);      // 8 MB [bh][64][2048]
  ushort_t* kp   = (ushort_t*)(ws + 27295744);      // 32 MB [bh][2048][256]
  ushort_t* Skv  = (ushort_t*)(ws + 60850176);      // 17.04 MB [bh][16][65][256]
  ushort_t* attb = (ushort_t*)(ws + 77889536);      // 8 MB
  const ushort_t* Wo = Wc + 786432;
  const ushort_t* Pc = Wc + 1048576;

  dim3 blk(256);
  cvt_w<<<520, blk, 0, stream>>>(wq, wk, wv, wo, proj, Wc);
  qkvgemm_k<<<dim3(64, 8, 3), blk, 0, stream>>>(query, key, value, Wc, bq, bk, bv, XHq, XHk, VT);
  cp2_k<<<dim3(NC, BH), blk, 0, stream>>>(XHk, Pc, VT, kp, Skv);
  prefix2_k<<<260, blk, 0, stream>>>(Skv);
  qkout3_k<<<dim3(NC, BH), dim3(512), 0, stream>>>(XHq, Pc, kp, VT, Skv, attb);
  gemmo_k<<<dim3(64, 8), blk, 0, stream>>>(attb, Wo, bo, (float*)d_out);
}

// Round 7
// 102.825 us; speedup vs baseline: 6.2737x; 1.0086x over previous
//
#include <hip/hip_runtime.h>
#include <stdint.h>

#define B_ 4
#define L_ 2048
#define H_ 8
#define DK 64
#define M_ 256
#define DIM_ 512
#define NTOK (B_ * L_)
#define CHK 128
#define NC (L_ / CHK)
#define BH (B_ * H_)
#define RATIO 0.0625f
#define STABC 1e-5f

typedef unsigned short ushort_t;
typedef __attribute__((ext_vector_type(8))) short bf8v;   // 8 bf16 = 4 VGPR
typedef __attribute__((ext_vector_type(4))) float f4v;    // MFMA accumulator

#define MFMA16(a, b, c) __builtin_amdgcn_mfma_f32_16x16x32_bf16(a, b, c, 0, 0, 0)

__device__ __forceinline__ ushort_t f2bf(float f) {
  uint32_t u = __float_as_uint(f);
  return (ushort_t)((u + 0x7fffu + ((u >> 16) & 1u)) >> 16);
}
__device__ __forceinline__ float bf2f(ushort_t u) { return __uint_as_float(((uint32_t)u) << 16); }

__device__ __forceinline__ void gll16(const void* g, void* l) {
  __builtin_amdgcn_global_load_lds((const __attribute__((address_space(1))) void*)g,
                                   (__attribute__((address_space(3))) void*)l, 16, 0, 0);
}

// XOR-swizzled LDS tiles; row strides 128/256/512 B
__device__ __forceinline__ bf8v ldfrag(const ushort_t* base, int row, int cb) {
  return *(const bf8v*)((const char*)base + row * 128 + (cb ^ ((row & 7) << 4)));
}
__device__ __forceinline__ bf8v ldfrag256(const ushort_t* base, int row, int cb) {
  return *(const bf8v*)((const char*)base + row * 256 + (cb ^ ((row & 7) << 4)));
}
__device__ __forceinline__ bf8v ldfrag512(const ushort_t* base, int row, int cb) {
  return *(const bf8v*)((const char*)base + row * 512 + (cb ^ ((row & 7) << 4)));
}

// ---------------- bf16 convert of weights + proj only ----------------
__global__ __launch_bounds__(256) void cvt_w(const float* __restrict__ wq, const float* __restrict__ wk,
                                             const float* __restrict__ wv, const float* __restrict__ wo,
                                             const float* __restrict__ pj, ushort_t* __restrict__ d) {
  int i = (blockIdx.x * 256 + threadIdx.x) * 8;   // 520 blocks covers 1,064,960 elems exactly
  const float* s;
  int off;
  if (i < 262144)       { s = wq; off = i; }
  else if (i < 524288)  { s = wk; off = i - 262144; }
  else if (i < 786432)  { s = wv; off = i - 524288; }
  else if (i < 1048576) { s = wo; off = i - 786432; }
  else                  { s = pj; off = i - 1048576; }
  float4 a = *(const float4*)(s + off);
  float4 b = *(const float4*)(s + off + 4);
  union { ushort_t u[8]; uint4 vv; } o;
  o.u[0] = f2bf(a.x); o.u[1] = f2bf(a.y); o.u[2] = f2bf(a.z); o.u[3] = f2bf(a.w);
  o.u[4] = f2bf(b.x); o.u[5] = f2bf(b.y); o.u[6] = f2bf(b.z); o.u[7] = f2bf(b.w);
  *(uint4*)(d + i) = o.vv;
}

// ---------------- fused Q/K/V projection GEMM, fp32 input reg-staged to bf16 LDS ----------------
// grid (64, 8, 3): z=0 query->XHq, z=1 key->XHk, z=2 value->VT (transposed head-slices)
// LDS: single 24576-B buffer; Tt (V-transpose) aliases As/Bs after the final K-loop barrier.
__global__ __launch_bounds__(256) void qkvgemm_k(const float* __restrict__ q, const float* __restrict__ k,
                                                 const float* __restrict__ v, const ushort_t* __restrict__ Wc,
                                                 const float* __restrict__ bq, const float* __restrict__ bk,
                                                 const float* __restrict__ bv, ushort_t* __restrict__ XHq,
                                                 ushort_t* __restrict__ XHk, ushort_t* __restrict__ VT) {
  __shared__ char SB[24576];
  ushort_t* As = (ushort_t*)SB;             // 16384 B: [128][64] swz
  ushort_t* Bs = (ushort_t*)(SB + 16384);   //  8192 B: [64][64] swz
  ushort_t* Tt = (ushort_t*)SB;             // 17408 B: [64][136] (epilogue only, z==2)
  const int z = blockIdx.z;
  const float* X = (z == 0) ? q : (z == 1) ? k : v;
  const ushort_t* Bw = Wc + (size_t)z * 262144;
  const float* bias = (z == 0) ? bq : (z == 1) ? bk : bv;
  const int tid = threadIdx.x, lane = tid & 63, w = tid >> 6;
  const int bm = blockIdx.x * 128, bn = blockIdx.y * 64;
  const int srow = w * 8 + (lane >> 3);
  const int scol = (((lane & 7) * 16) ^ ((lane >> 3) << 4)) >> 1;
  const int wr = (w >> 1) * 64, wc = (w & 1) * 32;
  const int fr = lane & 15, ks = lane >> 4, fq = lane >> 4;
  f4v acc[4][2] = {};
  for (int k0 = 0; k0 < DIM_; k0 += 64) {
    // B (weights, bf16) async
#pragma unroll
    for (int i = 0; i < 2; ++i)
      gll16(Bw + (size_t)(bn + i * 32 + srow) * DIM_ + k0 + scol, (char*)Bs + i * 4096 + w * 1024);
    // A (fp32 -> bf16, swizzled ds_write)
#pragma unroll
    for (int i = 0; i < 4; ++i) {
      int e = tid + i * 256;
      int r = e >> 3, g = e & 7;
      const float* src = X + (size_t)(bm + r) * DIM_ + k0 + g * 8;
      float4 f0 = *(const float4*)src;
      float4 f1 = *(const float4*)(src + 4);
      union { ushort_t u[8]; bf8v v8; } pk;
      pk.u[0] = f2bf(f0.x); pk.u[1] = f2bf(f0.y); pk.u[2] = f2bf(f0.z); pk.u[3] = f2bf(f0.w);
      pk.u[4] = f2bf(f1.x); pk.u[5] = f2bf(f1.y); pk.u[6] = f2bf(f1.z); pk.u[7] = f2bf(f1.w);
      *(bf8v*)((char*)As + r * 128 + ((g * 16) ^ ((r & 7) << 4))) = pk.v8;
    }
    __syncthreads();
#pragma unroll
    for (int kk = 0; kk < 2; ++kk) {
      const int cb = kk * 64 + ks * 16;
      bf8v av[4], bv2[2];
#pragma unroll
      for (int m = 0; m < 4; ++m) av[m] = ldfrag(As, wr + m * 16 + fr, cb);
#pragma unroll
      for (int n = 0; n < 2; ++n) bv2[n] = ldfrag(Bs, wc + n * 16 + fr, cb);
#pragma unroll
      for (int m = 0; m < 4; ++m)
#pragma unroll
        for (int n = 0; n < 2; ++n) acc[m][n] = MFMA16(av[m], bv2[n], acc[m][n]);
    }
    __syncthreads();
  }
  if (z == 2) {   // V path: transpose head slice -> VT[bh][64][2048] (Tt aliases As/Bs, safe post-barrier)
#pragma unroll
    for (int m = 0; m < 4; ++m)
#pragma unroll
      for (int n = 0; n < 2; ++n) {
        int cl = wc + n * 16 + fr;
        float bsv = bias[bn + cl];
#pragma unroll
        for (int j = 0; j < 4; ++j) {
          int rl = wr + m * 16 + fq * 4 + j;
          Tt[cl * 136 + rl] = f2bf(acc[m][n][j] + bsv);
        }
      }
    __syncthreads();
    const int d = tid >> 2, seg = tid & 3;
    const int b = bm >> 11, h = blockIdx.y, l0 = bm & 2047;
    size_t vbase = ((size_t)((b * 8 + h) * 64 + d)) * L_ + l0 + seg * 32;
#pragma unroll
    for (int qq = 0; qq < 4; ++qq)
      *(uint4*)&VT[vbase + qq * 8] = *(const uint4*)&Tt[d * 136 + seg * 32 + qq * 8];
  } else {
    ushort_t* Y = (z == 0) ? XHq : XHk;
#pragma unroll
    for (int m = 0; m < 4; ++m)
#pragma unroll
      for (int n = 0; n < 2; ++n) {
        int col = bn + wc + n * 16 + fr;
        float bsv = bias[col];
#pragma unroll
        for (int j = 0; j < 4; ++j) {
          int row = bm + wr + m * 16 + fq * 4 + j;
          Y[(size_t)row * DIM_ + col] = f2bf(acc[m][n][j] + bsv);
        }
      }
  }
}

// ---------------- cp2: fused kp-feature + per-chunk partials ----------------
__global__ __launch_bounds__(256) void cp2_k(const ushort_t* __restrict__ XHk, const ushort_t* __restrict__ P,
                                             const ushort_t* __restrict__ VT, ushort_t* __restrict__ kp,
                                             ushort_t* __restrict__ S) {
  __shared__ ushort_t Ps[256 * 64];    // proj (32 KB)
  __shared__ ushort_t Xs[128 * 64];    // XHk chunk, then [VT;ones] (16 KB)
  __shared__ ushort_t Kt[256 * 128];   // kpT [m][l], 256B rows swizzled (64 KB)
  const int ci = blockIdx.x, bh = blockIdx.y;
  const int b = bh >> 3, h = bh & 7;
  const int tid = threadIdx.x, lane = tid & 63, w = tid >> 6;
  const int srow = w * 8 + (lane >> 3);
  const int scol = (((lane & 7) * 16) ^ ((lane >> 3) << 4)) >> 1;
  const int fr = lane & 15, ks = lane >> 4, fq = lane >> 4;
  const int l0 = ci * CHK;
#pragma unroll
  for (int i = 0; i < 8; ++i)
    gll16(P + (size_t)(i * 32 + srow) * 64 + scol, (char*)Ps + i * 4096 + w * 1024);
#pragma unroll
  for (int i = 0; i < 4; ++i)
    gll16(XHk + (size_t)(b * L_ + l0 + i * 32 + srow) * DIM_ + h * 64 + scol, (char*)Xs + i * 4096 + w * 1024);
  __syncthreads();
  {
    f4v acc[4][8] = {};
#pragma unroll
    for (int kk = 0; kk < 2; ++kk) {
      const int cb = kk * 64 + ks * 16;
      bf8v av[4], bv[8];
#pragma unroll
      for (int m = 0; m < 4; ++m) av[m] = ldfrag(Ps, w * 64 + m * 16 + fr, cb);
#pragma unroll
      for (int n = 0; n < 8; ++n) bv[n] = ldfrag(Xs, n * 16 + fr, cb);
#pragma unroll
      for (int m = 0; m < 4; ++m)
#pragma unroll
        for (int n = 0; n < 8; ++n) acc[m][n] = MFMA16(av[m], bv[n], acc[m][n]);
    }
#pragma unroll
    for (int m = 0; m < 4; ++m)
#pragma unroll
      for (int n = 0; n < 8; ++n) {
        const int mb = w * 64 + m * 16 + fq * 4;
        const int ll = n * 16 + fr;
        ushort_t bvv[4];
#pragma unroll
        for (int j = 0; j < 4; ++j) {
          float v = fmaxf(RATIO * acc[m][n][j], 0.f) + STABC;
          bvv[j] = f2bf(v);
          *(ushort_t*)((char*)Kt + (mb + j) * 256 + ((ll * 2) ^ (((mb + j) & 7) << 4))) = bvv[j];
        }
        uint2 pk;
        pk.x = (uint32_t)bvv[0] | ((uint32_t)bvv[1] << 16);
        pk.y = (uint32_t)bvv[2] | ((uint32_t)bvv[3] << 16);
        *(uint2*)(kp + ((size_t)bh * L_ + l0 + ll) * M_ + mb) = pk;
      }
  }
  __syncthreads();
  f4v accS[5][4] = {};
  for (int kt = 0; kt < 2; ++kt) {
#pragma unroll
    for (int i = 0; i < 2; ++i)
      gll16(VT + ((size_t)bh * 64 + i * 32 + srow) * L_ + l0 + kt * 64 + scol, (char*)Xs + i * 4096 + w * 1024);
    if (tid < 32) ((uint32_t*)Xs)[2048 + tid] = 0x3f803f80u;
    __syncthreads();
#pragma unroll
    for (int kk = 0; kk < 2; ++kk) {
      const int cbA = kk * 64 + ks * 16;
      const int cbK = kt * 128 + kk * 64 + ks * 16;
      bf8v av[5], bv[4];
#pragma unroll
      for (int a = 0; a < 5; ++a) av[a] = ldfrag(Xs, a * 16 + fr, cbA);
#pragma unroll
      for (int n = 0; n < 4; ++n) bv[n] = ldfrag256(Kt, w * 64 + n * 16 + fr, cbK);
#pragma unroll
      for (int a = 0; a < 5; ++a)
#pragma unroll
        for (int n = 0; n < 4; ++n) accS[a][n] = MFMA16(av[a], bv[n], accS[a][n]);
    }
    __syncthreads();
  }
  const size_t base = ((size_t)bh * NC + ci) * 65;
#pragma unroll
  for (int a = 0; a < 5; ++a)
#pragma unroll
    for (int n = 0; n < 4; ++n)
#pragma unroll
      for (int j = 0; j < 4; ++j) {
        int row = a * 16 + fq * 4 + j;
        if (row < 65) S[(base + row) * M_ + w * 64 + n * 16 + fr] = f2bf(accS[a][n][j]);
      }
}

// ---------------- exclusive prefix over chunks ----------------
__global__ __launch_bounds__(256) void prefix2_k(ushort_t* __restrict__ S) {
  const int g = blockIdx.x * 256 + threadIdx.x;
  const int bh = g / 2080, r = g - bh * 2080;
  ushort_t* base = S + (size_t)bh * (NC * 65 * M_) + (size_t)r * 8;
  uint4 v[16];
#pragma unroll
  for (int ci = 0; ci < NC; ++ci) v[ci] = *(const uint4*)(base + (size_t)ci * (65 * M_));
  float c[8] = {};
#pragma unroll
  for (int ci = 0; ci < NC; ++ci) {
    union { uint4 u; ushort_t s[8]; } in, out;
    in.u = v[ci];
#pragma unroll
    for (int e = 0; e < 8; ++e) {
      float t = bf2f(in.s[e]);
      out.s[e] = f2bf(c[e]);
      c[e] += t;
    }
    *(uint4*)(base + (size_t)ci * (65 * M_)) = out.u;
  }
}

// ---------------- qkout3: in-LDS qp-feature + QK^T + qp@S + A@[VT;1] ----------------
__global__ __launch_bounds__(512) void qkout3_k(const ushort_t* __restrict__ XHq, const ushort_t* __restrict__ P,
                                                const ushort_t* __restrict__ kp, const ushort_t* __restrict__ VT,
                                                const ushort_t* __restrict__ S, ushort_t* __restrict__ attn) {
  __shared__ char LB[114688];
  ushort_t* Qp = (ushort_t*)LB;
  ushort_t* R1 = (ushort_t*)(LB + 65536);
  ushort_t* R2 = (ushort_t*)(LB + 98304);
  const int ci = blockIdx.x, bh = blockIdx.y;
  const int b = bh >> 3, h = bh & 7;
  const int tid = threadIdx.x, lane = tid & 63, w = tid >> 6;   // w 0..7
  const int srow = w * 8 + (lane >> 3);
  const int scol = (((lane & 7) * 16) ^ ((lane >> 3) << 4)) >> 1;
  const int fr = lane & 15, ks = lane >> 4, fq = lane >> 4;
  const int l0 = ci * CHK;
  const size_t rowb = (size_t)bh * L_ + l0;            // [bh][L] index: kp only!
  const size_t tokb = (size_t)b * L_ + l0;             // [token] index: XHq / attn
  const size_t sbase = ((size_t)bh * NC + ci) * 65;
  // ---- phase 0: stage proj + XHq chunk; compute qp -> Qp ----
#pragma unroll
  for (int i = 0; i < 4; ++i)
    gll16(P + (size_t)(i * 64 + srow) * 64 + scol, (char*)R1 + i * 8192 + w * 1024);
#pragma unroll
  for (int i = 0; i < 2; ++i)
    gll16(XHq + (tokb + i * 64 + srow) * DIM_ + h * 64 + scol, (char*)R2 + i * 8192 + w * 1024);
  __syncthreads();
  {
    f4v accF[2][8] = {};
#pragma unroll
    for (int kk = 0; kk < 2; ++kk) {
      const int cb = kk * 64 + ks * 16;
      bf8v av[2], bv[8];
#pragma unroll
      for (int m = 0; m < 2; ++m) av[m] = ldfrag(R1, w * 32 + m * 16 + fr, cb);
#pragma unroll
      for (int n = 0; n < 8; ++n) bv[n] = ldfrag(R2, n * 16 + fr, cb);
#pragma unroll
      for (int m = 0; m < 2; ++m)
#pragma unroll
        for (int n = 0; n < 8; ++n) accF[m][n] = MFMA16(av[m], bv[n], accF[m][n]);
    }
#pragma unroll
    for (int m = 0; m < 2; ++m)
#pragma unroll
      for (int n = 0; n < 8; ++n) {
        const int mb = w * 32 + m * 16 + fq * 4;
        const int ll = n * 16 + fr;
        ushort_t bvv[4];
#pragma unroll
        for (int j = 0; j < 4; ++j)
          bvv[j] = f2bf(fmaxf(RATIO * accF[m][n][j], 0.f) + STABC);
        uint2 pk;
        pk.x = (uint32_t)bvv[0] | ((uint32_t)bvv[1] << 16);
        pk.y = (uint32_t)bvv[2] | ((uint32_t)bvv[3] << 16);
        *(uint2*)((char*)Qp + ll * 512 + ((mb * 2) ^ ((ll & 7) << 4))) = pk;
      }
  }
  __syncthreads();
  // ---- phase 1: QK^T (accA) + qp@[S;sk] (acc2), kt over 4 x 64 features ----
  const int qr = (w & 3) * 32, qc = (w >> 2) * 64;
  const int orow = w * 16;
  f4v accA[2][4] = {};
  f4v acc2[5] = {};
  for (int kt = 0; kt < 4; ++kt) {
#pragma unroll
    for (int i = 0; i < 2; ++i)
      gll16(kp + (rowb + i * 64 + srow) * M_ + kt * 64 + scol, (char*)R1 + i * 8192 + w * 1024);
    gll16(S + (sbase + srow) * M_ + kt * 64 + scol, (char*)R2 + w * 1024);
    if (tid < 32)
      ((uint32_t*)R2)[2048 + tid] = ((const uint32_t*)(S + (sbase + 64) * M_ + kt * 64))[tid];
    __syncthreads();
#pragma unroll
    for (int kk = 0; kk < 2; ++kk) {
      const int cb = kk * 64 + ks * 16;
      const int cbQ = kt * 128 + cb;
      bf8v aq[2], bk_[4], a2, sv[5];
#pragma unroll
      for (int m = 0; m < 2; ++m) aq[m] = ldfrag512(Qp, qr + m * 16 + fr, cbQ);
#pragma unroll
      for (int n = 0; n < 4; ++n) bk_[n] = ldfrag(R1, qc + n * 16 + fr, cb);
#pragma unroll
      for (int m = 0; m < 2; ++m)
#pragma unroll
        for (int n = 0; n < 4; ++n) accA[m][n] = MFMA16(aq[m], bk_[n], accA[m][n]);
      a2 = ldfrag512(Qp, orow + fr, cbQ);
#pragma unroll
      for (int n = 0; n < 5; ++n) sv[n] = ldfrag(R2, n * 16 + fr, cb);
#pragma unroll
      for (int n = 0; n < 5; ++n) acc2[n] = MFMA16(a2, sv[n], acc2[n]);
    }
    __syncthreads();
  }
  // ---- phase 2: masked A -> At ----
#pragma unroll
  for (int m = 0; m < 2; ++m)
#pragma unroll
    for (int n = 0; n < 4; ++n)
#pragma unroll
      for (int j = 0; j < 4; ++j) {
        int row = qr + m * 16 + fq * 4 + j;
        int col = qc + n * 16 + fr;
        float v = (col <= row) ? accA[m][n][j] : 0.f;
        *(ushort_t*)((char*)R1 + row * 256 + ((col * 2) ^ ((row & 7) << 4))) = f2bf(v);
      }
  __syncthreads();
  // ---- phase 3: A @ [VT; ones] ----
  for (int kt2 = 0; kt2 < 2; ++kt2) {
    gll16(VT + ((size_t)bh * 64 + srow) * L_ + l0 + kt2 * 64 + scol, (char*)R2 + w * 1024);
    if (tid < 32) ((uint32_t*)R2)[2048 + tid] = 0x3f803f80u;
    __syncthreads();
#pragma unroll
    for (int kk = 0; kk < 2; ++kk) {
      const int cb = kk * 64 + ks * 16;
      bf8v a3, sv[5];
      a3 = ldfrag256(R1, orow + fr, kt2 * 128 + cb);
#pragma unroll
      for (int n = 0; n < 5; ++n) sv[n] = ldfrag(R2, n * 16 + fr, cb);
#pragma unroll
      for (int n = 0; n < 5; ++n) acc2[n] = MFMA16(a3, sv[n], acc2[n]);
    }
    __syncthreads();
  }
  // ---- epilogue ----
  float dinv[4];
#pragma unroll
  for (int j = 0; j < 4; ++j) {
    float den = __shfl(acc2[4][j], (lane & 48));   // col 64 lives at fr==0
    dinv[j] = 1.f / den;
  }
#pragma unroll
  for (int n = 0; n < 4; ++n)
#pragma unroll
    for (int j = 0; j < 4; ++j) {
      int l = orow + fq * 4 + j;
      int col = h * 64 + n * 16 + fr;
      attn[(tokb + l) * DIM_ + col] = f2bf(acc2[n][j] * dinv[j]);
    }
}

// ---------------- output projection: fp32 out = attb @ Wo^T + bo ----------------
__global__ __launch_bounds__(256) void gemmo_k(const ushort_t* __restrict__ A, const ushort_t* __restrict__ Bw,
                                               const float* __restrict__ bias, float* __restrict__ Y) {
  __shared__ ushort_t As[128 * 64];
  __shared__ ushort_t Bs[64 * 64];
  const int tid = threadIdx.x, lane = tid & 63, w = tid >> 6;
  const int bm = blockIdx.x * 128, bn = blockIdx.y * 64;
  const int srow = w * 8 + (lane >> 3);
  const int scol = (((lane & 7) * 16) ^ ((lane >> 3) << 4)) >> 1;
  const int wr = (w >> 1) * 64, wc = (w & 1) * 32;
  const int fr = lane & 15, ks = lane >> 4, fq = lane >> 4;
  f4v acc[4][2] = {};
  for (int k0 = 0; k0 < DIM_; k0 += 64) {
#pragma unroll
    for (int i = 0; i < 4; ++i)
      gll16(A + (size_t)(bm + i * 32 + srow) * DIM_ + k0 + scol, (char*)As + i * 4096 + w * 1024);
#pragma unroll
    for (int i = 0; i < 2; ++i)
      gll16(Bw + (size_t)(bn + i * 32 + srow) * DIM_ + k0 + scol, (char*)Bs + i * 4096 + w * 1024);
    __syncthreads();
#pragma unroll
    for (int kk = 0; kk < 2; ++kk) {
      const int cb = kk * 64 + ks * 16;
      bf8v av[4], bv[2];
#pragma unroll
      for (int m = 0; m < 4; ++m) av[m] = ldfrag(As, wr + m * 16 + fr, cb);
#pragma unroll
      for (int n = 0; n < 2; ++n) bv[n] = ldfrag(Bs, wc + n * 16 + fr, cb);
#pragma unroll
      for (int m = 0; m < 4; ++m)
#pragma unroll
        for (int n = 0; n < 2; ++n) acc[m][n] = MFMA16(av[m], bv[n], acc[m][n]);
    }
    __syncthreads();
  }
#pragma unroll
  for (int m = 0; m < 4; ++m)
#pragma unroll
    for (int n = 0; n < 2; ++n) {
      int col = bn + wc + n * 16 + fr;
      float bsv = bias[col];
#pragma unroll
      for (int j = 0; j < 4; ++j) {
        int row = bm + wr + m * 16 + fq * 4 + j;
        Y[(size_t)row * DIM_ + col] = acc[m][n][j] + bsv;
      }
    }
}

extern "C" void kernel_launch(void* const* d_in, const int* in_sizes, int n_in,
                              void* d_out, int out_size, void* d_ws, size_t ws_size,
                              hipStream_t stream) {
  const float* query = (const float*)d_in[0];
  const float* key   = (const float*)d_in[1];
  const float* value = (const float*)d_in[2];
  const float* proj  = (const float*)d_in[3];
  const float* wq = (const float*)d_in[4];
  const float* bq = (const float*)d_in[5];
  const float* wk = (const float*)d_in[6];
  const float* bk = (const float*)d_in[7];
  const float* wv = (const float*)d_in[8];
  const float* bv = (const float*)d_in[9];
  const float* wo = (const float*)d_in[10];
  const float* bo = (const float*)d_in[11];

  char* ws = (char*)d_ws;
  ushort_t* Wc   = (ushort_t*)(ws);                 // weights+proj bf16: 2,129,920 B
  ushort_t* XHq  = (ushort_t*)(ws + 2129920);       // 8 MB
  ushort_t* XHk  = (ushort_t*)(ws + 10518528);      // 8 MB
  ushort_t* VT   = (ushort_t*)(ws + 18907136);      // 8 MB [bh][64][2048]
  ushort_t* kp   = (ushort_t*)(ws + 27295744);      // 32 MB [bh][2048][256]
  ushort_t* Skv  = (ushort_t*)(ws + 60850176);      // 17.04 MB [bh][16][65][256]
  ushort_t* attb = (ushort_t*)(ws + 77889536);      // 8 MB
  const ushort_t* Wo = Wc + 786432;
  const ushort_t* Pc = Wc + 1048576;

  dim3 blk(256);
  cvt_w<<<520, blk, 0, stream>>>(wq, wk, wv, wo, proj, Wc);
  qkvgemm_k<<<dim3(64, 8, 3), blk, 0, stream>>>(query, key, value, Wc, bq, bk, bv, XHq, XHk, VT);
  cp2_k<<<dim3(NC, BH), blk, 0, stream>>>(XHk, Pc, VT, kp, Skv);
  prefix2_k<<<260, blk, 0, stream>>>(Skv);
  qkout3_k<<<dim3(NC, BH), dim3(512), 0, stream>>>(XHq, Pc, kp, VT, Skv, attb);
  gemmo_k<<<dim3(64, 8), blk, 0, stream>>>(attb, Wo, bo, (float*)d_out);
}